// Round 8
// baseline (400.428 us; speedup 1.0000x reference)
//
#include <hip/hip_runtime.h>
#include <math.h>

// ---------------------------------------------------------------------------
// OptimizedProtoHyperFormer — round 8: K1 reverted to R6 (HBM-bound winner);
// k3a/k3b/k3c software-pipelined (reg-prefetch + double-buffered LDS B-tiles).
// B=32, IB=103, H=W=256, P=16, RB=8, DIM=192, DEPTH=3, FFH=384, NT=8192.
// ---------------------------------------------------------------------------

typedef __attribute__((ext_vector_type(8))) short bf16x8;
typedef __attribute__((ext_vector_type(4))) float f32x4;

__device__ __forceinline__ float wsum64(float v) {
#pragma unroll
  for (int o = 32; o > 0; o >>= 1) v += __shfl_xor(v, o, 64);
  return v;
}
__device__ __forceinline__ float sum16(float v) {
#pragma unroll
  for (int o = 8; o > 0; o >>= 1) v += __shfl_xor(v, o, 64);
  return v;
}
__device__ __forceinline__ float max16(float v) {
#pragma unroll
  for (int o = 8; o > 0; o >>= 1) v = fmaxf(v, __shfl_xor(v, o, 64));
  return v;
}
__device__ __forceinline__ float gelu_f(float x) {
  return 0.5f * x * (1.0f + erff(x * 0.7071067811865476f));
}
__device__ __forceinline__ ushort f2bf(float f) {
  union { float f; unsigned u; } v;
  v.f = f;
  unsigned r = v.u + 0x7FFFu + ((v.u >> 16) & 1u);
  return (ushort)(r >> 16);
}

// ---------------------------------------------------------------------------
// prep: bf16 transposes of all MFMA weights + band_w transpose.
// ---------------------------------------------------------------------------
__global__ __launch_bounds__(256) void prep_w(
    const float* __restrict__ qw, const float* __restrict__ vw,
    const float* __restrict__ f1w, const float* __restrict__ f2w,
    const float* __restrict__ r1_w, const float* __restrict__ r2_w,
    const float* __restrict__ key_w, const float* __restrict__ band_w,
    ushort* __restrict__ qwT, ushort* __restrict__ vwT,
    ushort* __restrict__ f1T, ushort* __restrict__ f2T,
    ushort* __restrict__ r1T, ushort* __restrict__ r2T,
    ushort* __restrict__ keyT, float* __restrict__ bandT) {
  const int i = blockIdx.x * 256 + threadIdx.x;
  if (i < 110592) {  // qw, vw: [3][192][192] -> [3][j][k]
    const int d = i / 36864, r = i % 36864;
    const int k = r / 192, c = r % 192;
    qwT[d * 36864 + c * 192 + k] = f2bf(qw[i]);
    vwT[d * 36864 + c * 192 + k] = f2bf(vw[i]);
  }
  if (i < 221184) {
    const int d = i / 73728, r = i % 73728;
    const int k = r / 384, j = r % 384;        // f1: [3][192][384] -> [3][384][192]
    f1T[d * 73728 + j * 192 + k] = f2bf(f1w[i]);
    const int k2 = r / 192, j2 = r % 192;      // f2: [3][384][192] -> [3][192][384]
    f2T[d * 73728 + j2 * 384 + k2] = f2bf(f2w[i]);
  }
  if (i < 24576) {  // r1: [192][128] -> [j:128][k:192]
    const int j = i / 192, k = i % 192;
    r1T[i] = f2bf(r1_w[k * 128 + j]);
  }
  if (i < 6144) {   // r2: [128][48] -> [j:48][k:128]
    const int j = i / 128, k = i % 128;
    r2T[i] = f2bf(r2_w[k * 48 + j]);
  }
  if (i < 43008) {  // key: [200][192] -> [j:192][k:224 padded]
    const int j = i / 224, k = i % 224;
    keyT[i] = (k < 200) ? f2bf(key_w[k * 192 + j]) : (ushort)0;
  }
  if (i < 824) {    // band_w: [8][103] -> [103][8]
    const int ch = i >> 3, c = i & 7;
    bandT[i] = band_w[c * 103 + ch];
  }
}

// ---------------------------------------------------------------------------
// K1 (R6 version — HBM-bound winner): fused band-reduction + depthwise conv.
// 512 blocks (batch x patch-row), 512 threads, 2-ch prefetch, nontemporal.
// ---------------------------------------------------------------------------
__global__ __launch_bounds__(512) void k1_band_dw(
    const float* __restrict__ x, const float* __restrict__ bandT,
    const float* __restrict__ band_b, const float* __restrict__ dw_w,
    float* __restrict__ dw_out) {
  const int blk = blockIdx.x;
  const int b = blk >> 4, ip = blk & 15;
  const int t = threadIdx.x;
  const int col4 = t & 63;
  const int j = col4 >> 2;
  const int qb = (col4 & 3) << 2;
  const int p0 = t >> 6;

  float acc[8][8];
#pragma unroll
  for (int e = 0; e < 8; ++e)
#pragma unroll
    for (int c = 0; c < 8; ++c) acc[e][c] = 0.f;

  const f32x4* xp = (const f32x4*)x + (size_t)b * (103 * 16384) + (size_t)ip * 1024;

  auto body = [&](const f32x4 v0, const f32x4 v1, const int ch) {
    const f32x4 wA = *(const f32x4*)&bandT[ch * 8];
    const f32x4 wB = *(const f32x4*)&bandT[ch * 8 + 4];
    const float bw[8] = {wA.x, wA.y, wA.z, wA.w, wB.x, wB.y, wB.z, wB.w};
#pragma unroll
    for (int c = 0; c < 8; ++c) {
      acc[0][c] = fmaf(v0.x, bw[c], acc[0][c]);
      acc[1][c] = fmaf(v0.y, bw[c], acc[1][c]);
      acc[2][c] = fmaf(v0.z, bw[c], acc[2][c]);
      acc[3][c] = fmaf(v0.w, bw[c], acc[3][c]);
      acc[4][c] = fmaf(v1.x, bw[c], acc[4][c]);
      acc[5][c] = fmaf(v1.y, bw[c], acc[5][c]);
      acc[6][c] = fmaf(v1.z, bw[c], acc[6][c]);
      acc[7][c] = fmaf(v1.w, bw[c], acc[7][c]);
    }
  };

  f32x4 p0v = __builtin_nontemporal_load(&xp[t]);
  f32x4 p1v = __builtin_nontemporal_load(&xp[t + 512]);
  f32x4 q0v = __builtin_nontemporal_load(&xp[t + 16384]);
  f32x4 q1v = __builtin_nontemporal_load(&xp[t + 16896]);
#pragma unroll 1
  for (int ch = 0; ch < 100; ch += 2) {
    const f32x4 r0 = __builtin_nontemporal_load(&xp[t + 2 * 16384]);
    const f32x4 r1 = __builtin_nontemporal_load(&xp[t + 2 * 16384 + 512]);
    const f32x4 s0 = __builtin_nontemporal_load(&xp[t + 3 * 16384]);
    const f32x4 s1 = __builtin_nontemporal_load(&xp[t + 3 * 16384 + 512]);
    body(p0v, p1v, ch);
    body(q0v, q1v, ch + 1);
    p0v = r0; p1v = r1; q0v = s0; q1v = s1;
    xp += 2 * 16384;
  }
  const f32x4 u0 = __builtin_nontemporal_load(&xp[t + 2 * 16384]);
  const f32x4 u1 = __builtin_nontemporal_load(&xp[t + 2 * 16384 + 512]);
  body(p0v, p1v, 100);
  body(q0v, q1v, 101);
  body(u0, u1, 102);

  float dwt[8];
#pragma unroll
  for (int c = 0; c < 8; ++c) dwt[c] = 0.f;
#pragma unroll
  for (int e = 0; e < 8; ++e) {
    const int pp = p0 + ((e >> 2) << 3);
    const int qq = qb + (e & 3);
#pragma unroll
    for (int c = 0; c < 8; ++c)
      dwt[c] = fmaf(dw_w[c * 256 + pp * 16 + qq], acc[e][c] + band_b[c], dwt[c]);
  }
#pragma unroll
  for (int c = 0; c < 8; ++c) {
    dwt[c] += __shfl_xor(dwt[c], 1, 64);
    dwt[c] += __shfl_xor(dwt[c], 2, 64);
  }
  __shared__ float part[8][16][8];
  if ((t & 3) == 0) {
#pragma unroll
    for (int c = 0; c < 8; ++c) part[t >> 6][j][c] = dwt[c];
  }
  __syncthreads();
  if (t < 128) {
    const int jj = t >> 3, c = t & 7;
    float s = 0.f;
#pragma unroll
    for (int w = 0; w < 8; ++w) s += part[w][jj][c];
    dw_out[(((size_t)b * 16 + ip) * 16 + jj) * 8 + c] = s;
  }
}

// ---------------------------------------------------------------------------
// K2 (MFMA): pw+LN -> router r1/r2 -> top2 -> proto mix -> keysT bf16.
// 32 tokens/block, 256 blocks, 4 waves. Unchanged.
// ---------------------------------------------------------------------------
__global__ __launch_bounds__(256) void k2_mfma(
    const float* __restrict__ dw, const float* __restrict__ pw_w,
    const float* __restrict__ pe_ln_w, const float* __restrict__ pe_ln_b,
    const float* __restrict__ spec_proto, const float* __restrict__ spat_proto,
    const ushort* __restrict__ r1T, const float* __restrict__ r1_b,
    const ushort* __restrict__ r2T, const float* __restrict__ r2_b,
    const ushort* __restrict__ keyT, const float* __restrict__ pos_bias,
    float* __restrict__ xb_out, ushort* __restrict__ keysT) {
  const int t = threadIdx.x;
  const int lane = t & 63, wid = t >> 6;
  const int wm = wid >> 1, wn = wid & 1;
  const int l15 = lane & 15, lg4 = lane >> 4;
  const int tok0 = blockIdx.x * 32;
  const int rl = wm * 16 + 4 * lg4;
  const int b = blockIdx.x >> 3;
  const int n0 = (blockIdx.x & 7) * 32;

  __shared__ float dw8s[32][8];
  __shared__ __align__(16) ushort s_xn[32][200];
  __shared__ __align__(16) ushort s_w[192][40];
  __shared__ __align__(16) ushort s_h[32][200];
  __shared__ __align__(16) ushort s_mix[32][232];
  __shared__ float s_rl[32][48];
  __shared__ float topwS[32][4];
  __shared__ int   topiS[32][4];

  dw8s[t >> 3][t & 7] = dw[((size_t)tok0 + (t >> 3)) * 8 + (t & 7)];
  __syncthreads();

#pragma unroll
  for (int half = 0; half < 2; ++half) {
    const int tt = half * 16 + (t >> 4), lg = t & 15;
    float pre[12], sm = 0.f;
#pragma unroll
    for (int m = 0; m < 12; ++m) {
      const int d = lg + 16 * m;
      const f32x4 pa = *(const f32x4*)&pw_w[d * 8];
      const f32x4 pb = *(const f32x4*)&pw_w[d * 8 + 4];
      float p = pa.x * dw8s[tt][0] + pa.y * dw8s[tt][1] + pa.z * dw8s[tt][2] +
                pa.w * dw8s[tt][3] + pb.x * dw8s[tt][4] + pb.y * dw8s[tt][5] +
                pb.z * dw8s[tt][6] + pb.w * dw8s[tt][7];
      pre[m] = p;
      sm += p;
    }
    sm = sum16(sm);
    const float mean = sm * (1.f / 192.f);
    float vv = 0.f;
#pragma unroll
    for (int m = 0; m < 12; ++m) {
      const float d0 = pre[m] - mean;
      vv = fmaf(d0, d0, vv);
    }
    vv = sum16(vv);
    const float inv = rsqrtf(vv * (1.f / 192.f) + 1e-5f);
#pragma unroll
    for (int m = 0; m < 12; ++m) {
      const int d = lg + 16 * m;
      const float xv = (pre[m] - mean) * inv * pe_ln_w[d] + pe_ln_b[d];
      s_xn[tt][d] = f2bf(xv);
      xb_out[((size_t)tok0 + tt) * 192 + d] = xv;
    }
  }
  __syncthreads();

  {
    f32x4 hacc[4];
#pragma unroll
    for (int f = 0; f < 4; ++f) hacc[f] = (f32x4){0.f, 0.f, 0.f, 0.f};
#pragma unroll 1
    for (int ks = 0; ks < 6; ++ks) {
#pragma unroll
      for (int i = 0; i < 2; ++i) {
        const int lin = t + 256 * i;
        const int row = lin >> 2, c8 = (lin & 3) * 8;
        *(uint4*)&s_w[row][c8] = *(const uint4*)&r1T[row * 192 + ks * 32 + c8];
      }
      __syncthreads();
      const bf16x8 a = *(const bf16x8*)&s_xn[wm * 16 + l15][ks * 32 + 8 * lg4];
#pragma unroll
      for (int f = 0; f < 4; ++f) {
        const bf16x8 bb = *(const bf16x8*)&s_w[wn * 64 + 16 * f + l15][8 * lg4];
        hacc[f] = __builtin_amdgcn_mfma_f32_16x16x32_bf16(a, bb, hacc[f], 0, 0, 0);
      }
      __syncthreads();
    }
#pragma unroll
    for (int f = 0; f < 4; ++f) {
      const int col = wn * 64 + 16 * f + l15;
#pragma unroll
      for (int reg = 0; reg < 4; ++reg)
        s_h[rl + reg][col] = f2bf(gelu_f(hacc[f][reg] + r1_b[col]));
    }
  }
  __syncthreads();

  {
    f32x4 racc[2];
    racc[0] = (f32x4){0.f, 0.f, 0.f, 0.f};
    racc[1] = (f32x4){0.f, 0.f, 0.f, 0.f};
#pragma unroll 1
    for (int ks = 0; ks < 4; ++ks) {
      if (t < 192) {
        const int row = t >> 2, c8 = (t & 3) * 8;
        *(uint4*)&s_w[row][c8] = *(const uint4*)&r2T[row * 128 + ks * 32 + c8];
      }
      __syncthreads();
      const bf16x8 a = *(const bf16x8*)&s_h[wm * 16 + l15][ks * 32 + 8 * lg4];
      if (wn == 0) {
#pragma unroll
        for (int f = 0; f < 2; ++f) {
          const bf16x8 bb = *(const bf16x8*)&s_w[16 * f + l15][8 * lg4];
          racc[f] = __builtin_amdgcn_mfma_f32_16x16x32_bf16(a, bb, racc[f], 0, 0, 0);
        }
      } else {
        const bf16x8 bb = *(const bf16x8*)&s_w[32 + l15][8 * lg4];
        racc[0] = __builtin_amdgcn_mfma_f32_16x16x32_bf16(a, bb, racc[0], 0, 0, 0);
      }
      __syncthreads();
    }
    if (wn == 0) {
#pragma unroll
      for (int f = 0; f < 2; ++f) {
        const int col = 16 * f + l15;
#pragma unroll
        for (int reg = 0; reg < 4; ++reg)
          s_rl[rl + reg][col] = racc[f][reg] + r2_b[col];
      }
    } else {
      const int col = 32 + l15;
#pragma unroll
      for (int reg = 0; reg < 4; ++reg)
        s_rl[rl + reg][col] = racc[0][reg] + r2_b[col];
    }
  }
  __syncthreads();

  if (t < 64) {
    const int tt = t >> 1, half = t & 1;
    const float* base = &s_rl[tt][half * 24];
    float v0 = -1e30f, v1 = -1e30f;
    int i0 = 0, i1 = 0;
    for (int k = 0; k < 24; ++k) {
      const float vv = base[k];
      if (vv > v0) { v1 = v0; i1 = i0; v0 = vv; i0 = k; }
      else if (vv > v1) { v1 = vv; i1 = k; }
    }
    const float tau = (float)(0.07 + 1e-8);
    const float e1 = expf((v1 - v0) / tau);
    const float inv = 1.f / (1.f + e1);
    topwS[tt][half * 2] = inv;
    topwS[tt][half * 2 + 1] = e1 * inv;
    topiS[tt][half * 2] = i0;
    topiS[tt][half * 2 + 1] = i1;
  }
  __syncthreads();

#pragma unroll
  for (int r = 0; r < 28; ++r) {
    const int f = t + 256 * r;  // 32*224 = 7168 exact
    const int tok = f / 224, c = f % 224;
    float val = 0.f;
    if (c < 8) {
      val = topwS[tok][0] * spec_proto[topiS[tok][0] * 8 + c] +
            topwS[tok][1] * spec_proto[topiS[tok][1] * 8 + c];
    } else if (c < 200) {
      const int cc = c - 8;
      val = topwS[tok][2] * spat_proto[topiS[tok][2] * 192 + cc] +
            topwS[tok][3] * spat_proto[topiS[tok][3] * 192 + cc];
    }
    s_mix[tok][c] = f2bf(val);
  }
  __syncthreads();

  {
    f32x4 kacc[6];
#pragma unroll
    for (int f = 0; f < 6; ++f) kacc[f] = (f32x4){0.f, 0.f, 0.f, 0.f};
#pragma unroll 1
    for (int ks = 0; ks < 7; ++ks) {
#pragma unroll
      for (int i = 0; i < 3; ++i) {
        const int lin = t + 256 * i;
        const int row = lin >> 2, c8 = (lin & 3) * 8;
        *(uint4*)&s_w[row][c8] = *(const uint4*)&keyT[row * 224 + ks * 32 + c8];
      }
      __syncthreads();
      const bf16x8 a = *(const bf16x8*)&s_mix[wm * 16 + l15][ks * 32 + 8 * lg4];
#pragma unroll
      for (int f = 0; f < 6; ++f) {
        const bf16x8 bb = *(const bf16x8*)&s_w[wn * 96 + 16 * f + l15][8 * lg4];
        kacc[f] = __builtin_amdgcn_mfma_f32_16x16x32_bf16(a, bb, kacc[f], 0, 0, 0);
      }
      __syncthreads();
    }
#pragma unroll
    for (int f = 0; f < 6; ++f) {
      const int col = wn * 96 + 16 * f + l15;
#pragma unroll
      for (int reg = 0; reg < 4; ++reg)
        keysT[((size_t)b * 192 + col) * 256 + n0 + rl + reg] =
            f2bf(kacc[f][reg] + pos_bias[col]);
    }
  }
}

// ---------------------------------------------------------------------------
// K3a (MFMA, reg-prefetch): LN -> xn bf16; q,v; softmax(q); vT bf16.
// ---------------------------------------------------------------------------
__global__ __launch_bounds__(256) void k3a_mfma(
    const float* __restrict__ xb, const float* __restrict__ lnw,
    const float* __restrict__ lnb, const ushort* __restrict__ qwT,
    const ushort* __restrict__ vwT, ushort* __restrict__ qs_bf,
    ushort* __restrict__ vT, int depth) {
  const int t = threadIdx.x;
  const int lane = t & 63, wid = t >> 6;
  const int wm = wid >> 1, wn = wid & 1;
  const int l15 = lane & 15, lg4 = lane >> 4;
  const int tok0 = blockIdx.x * 32;
  const int b = blockIdx.x >> 3;
  const int n0 = (blockIdx.x & 7) * 32;

  __shared__ __align__(16) char smem[12800 + 30720];
  ushort (*s_xn)[200] = (ushort(*)[200])smem;
  ushort (*s_wq)[40] = (ushort(*)[40])(smem + 12800);
  ushort (*s_wv)[40] = (ushort(*)[40])(smem + 12800 + 15360);
  float (*s_q)[196] = (float(*)[196])(smem + 12800);

  const float* lw = lnw + depth * 192;
  const float* lb = lnb + depth * 192;
#pragma unroll
  for (int half = 0; half < 2; ++half) {
    const int tt = half * 16 + (t >> 4);
    const int lg = t & 15;
    const float* xrow = xb + ((size_t)tok0 + tt) * 192;
    float vals[12], sm = 0.f;
#pragma unroll
    for (int m = 0; m < 12; ++m) {
      vals[m] = xrow[lg + 16 * m];
      sm += vals[m];
    }
    sm = sum16(sm);
    const float mean = sm * (1.f / 192.f);
    float vv = 0.f;
#pragma unroll
    for (int m = 0; m < 12; ++m) {
      const float d0 = vals[m] - mean;
      vv = fmaf(d0, d0, vv);
    }
    vv = sum16(vv);
    const float inv = rsqrtf(vv * (1.f / 192.f) + 1e-5f);
#pragma unroll
    for (int m = 0; m < 12; ++m) {
      const int d = lg + 16 * m;
      s_xn[tt][d] = f2bf((vals[m] - mean) * inv * lw[d] + lb[d]);
    }
  }

  const ushort* qbase = qwT + depth * 36864;
  const ushort* vbase = vwT + depth * 36864;
  // prologue: stage ks=0 directly (combined with s_xn barrier)
#pragma unroll
  for (int i = 0; i < 3; ++i) {
    const int idx = t + 256 * i;
    const int row = idx >> 2, c4 = (idx & 3) * 8;
    *(uint4*)&s_wq[row][c4] = *(const uint4*)&qbase[row * 192 + c4];
    *(uint4*)&s_wv[row][c4] = *(const uint4*)&vbase[row * 192 + c4];
  }
  __syncthreads();

  f32x4 aq[6], av[6];
#pragma unroll
  for (int f = 0; f < 6; ++f) {
    aq[f] = (f32x4){0.f, 0.f, 0.f, 0.f};
    av[f] = (f32x4){0.f, 0.f, 0.f, 0.f};
  }
  uint4 preq[3], prev_[3];
#pragma unroll 1
  for (int ks = 0; ks < 6; ++ks) {
    if (ks < 5) {
#pragma unroll
      for (int i = 0; i < 3; ++i) {
        const int idx = t + 256 * i;
        const int row = idx >> 2, c4 = (idx & 3) * 8;
        preq[i] = *(const uint4*)&qbase[row * 192 + (ks + 1) * 32 + c4];
        prev_[i] = *(const uint4*)&vbase[row * 192 + (ks + 1) * 32 + c4];
      }
    }
    const bf16x8 a = *(const bf16x8*)&s_xn[wm * 16 + l15][ks * 32 + 8 * lg4];
#pragma unroll
    for (int f = 0; f < 6; ++f) {
      const bf16x8 bq = *(const bf16x8*)&s_wq[wn * 96 + 16 * f + l15][8 * lg4];
      const bf16x8 bv = *(const bf16x8*)&s_wv[wn * 96 + 16 * f + l15][8 * lg4];
      aq[f] = __builtin_amdgcn_mfma_f32_16x16x32_bf16(a, bq, aq[f], 0, 0, 0);
      av[f] = __builtin_amdgcn_mfma_f32_16x16x32_bf16(a, bv, av[f], 0, 0, 0);
    }
    __syncthreads();
    if (ks < 5) {
#pragma unroll
      for (int i = 0; i < 3; ++i) {
        const int idx = t + 256 * i;
        const int row = idx >> 2, c4 = (idx & 3) * 8;
        *(uint4*)&s_wq[row][c4] = preq[i];
        *(uint4*)&s_wv[row][c4] = prev_[i];
      }
      __syncthreads();
    }
  }

  const int rl = wm * 16 + 4 * lg4;
#pragma unroll
  for (int f = 0; f < 6; ++f) {
    const int col = wn * 96 + 16 * f + l15;
#pragma unroll
    for (int reg = 0; reg < 4; ++reg) {
      vT[((size_t)b * 192 + col) * 256 + n0 + rl + reg] = f2bf(av[f][reg]);
      s_q[rl + reg][col] = aq[f][reg];
    }
  }
  __syncthreads();

#pragma unroll
  for (int half = 0; half < 2; ++half) {
    const int tt = half * 16 + (t >> 4);
    const int lg = t & 15;
    float vals[12], mx = -1e30f;
#pragma unroll
    for (int m = 0; m < 12; ++m) {
      vals[m] = s_q[tt][lg + 16 * m];
      mx = fmaxf(mx, vals[m]);
    }
    mx = max16(mx);
    float s = 0.f;
#pragma unroll
    for (int m = 0; m < 12; ++m) {
      vals[m] = expf(vals[m] - mx);
      s += vals[m];
    }
    s = sum16(s);
    const float inv = 1.f / s;
#pragma unroll
    for (int m = 0; m < 12; ++m)
      qs_bf[((size_t)tok0 + tt) * 192 + lg + 16 * m] = f2bf(vals[m] * inv);
  }
}

// ---------------------------------------------------------------------------
// K3b (MFMA, double-buffered pipeline): KV^T = vT @ keysT^T per batch, K=256.
// Grid: 32 batches x 6 d-tiles = 192 blocks, 4 waves, output kvT bf16.
// ---------------------------------------------------------------------------
__global__ __launch_bounds__(256) void k3b_mfma(
    const ushort* __restrict__ vT, const ushort* __restrict__ keysT,
    ushort* __restrict__ kvT) {
  const int t = threadIdx.x;
  const int lane = t & 63, wid = t >> 6;
  const int wm = wid >> 1, wn = wid & 1;
  const int l15 = lane & 15, lg4 = lane >> 4;
  const int b = blockIdx.x / 6;
  const int d0 = (blockIdx.x % 6) * 32;

  __shared__ __align__(16) ushort s_a[32][264];     // vT tile: 32 x 256
  __shared__ __align__(16) ushort s_w[2][192][40];  // keysT stage dbuf

  const ushort* kbase = keysT + (size_t)b * 192 * 256;
  uint4 pre[3];
  int cur = 0;

  // prologue: tile 0 + s_a stage, one barrier
#pragma unroll
  for (int i = 0; i < 3; ++i) {
    const int idx = t + 256 * i;
    const int row = idx >> 2, c4 = (idx & 3) * 8;
    pre[i] = *(const uint4*)&kbase[row * 256 + c4];
  }
  const ushort* vbase = vT + ((size_t)b * 192 + d0) * 256;
#pragma unroll
  for (int i = 0; i < 4; ++i) {
    const int idx = t + 256 * i;
    const int row = idx >> 5, c8 = (idx & 31) * 8;
    *(uint4*)&s_a[row][c8] = *(const uint4*)&vbase[row * 256 + c8];
  }
#pragma unroll
  for (int i = 0; i < 3; ++i) {
    const int idx = t + 256 * i;
    const int row = idx >> 2, c4 = (idx & 3) * 8;
    *(uint4*)&s_w[0][row][c4] = pre[i];
  }
  __syncthreads();

  f32x4 acc[6];
#pragma unroll
  for (int f = 0; f < 6; ++f) acc[f] = (f32x4){0.f, 0.f, 0.f, 0.f};
#pragma unroll 1
  for (int ks = 0; ks < 8; ++ks) {
    if (ks < 7) {
#pragma unroll
      for (int i = 0; i < 3; ++i) {
        const int idx = t + 256 * i;
        const int row = idx >> 2, c4 = (idx & 3) * 8;
        pre[i] = *(const uint4*)&kbase[row * 256 + (ks + 1) * 32 + c4];
      }
    }
    const bf16x8 a = *(const bf16x8*)&s_a[wm * 16 + l15][ks * 32 + 8 * lg4];
#pragma unroll
    for (int f = 0; f < 6; ++f) {
      const bf16x8 bb = *(const bf16x8*)&s_w[cur][wn * 96 + 16 * f + l15][8 * lg4];
      acc[f] = __builtin_amdgcn_mfma_f32_16x16x32_bf16(a, bb, acc[f], 0, 0, 0);
    }
    if (ks < 7) {
#pragma unroll
      for (int i = 0; i < 3; ++i) {
        const int idx = t + 256 * i;
        const int row = idx >> 2, c4 = (idx & 3) * 8;
        *(uint4*)&s_w[cur ^ 1][row][c4] = pre[i];
      }
    }
    __syncthreads();
    cur ^= 1;
  }

  const int rl = wm * 16 + 4 * lg4;
#pragma unroll
  for (int f = 0; f < 6; ++f) {
    const int col = wn * 96 + 16 * f + l15;
#pragma unroll
    for (int reg = 0; reg < 4; ++reg)
      kvT[((size_t)b * 192 + d0 + rl + reg) * 192 + col] = f2bf(acc[f][reg]);
  }
}

// ---------------------------------------------------------------------------
// K3c (MFMA, chained double-buffered pipeline): o1 = qs@KV; residual; LN;
// FFN; residual. 32 tokens/block, 256 blocks.
// ---------------------------------------------------------------------------
__global__ __launch_bounds__(256) void k3c_mfma(
    float* __restrict__ xb, const ushort* __restrict__ qs_bf,
    const ushort* __restrict__ kvT, const float* __restrict__ lnw,
    const float* __restrict__ lnb, const ushort* __restrict__ f1T,
    const ushort* __restrict__ f2T, const float* __restrict__ f1b,
    const float* __restrict__ f2b, const float* __restrict__ g1,
    const float* __restrict__ g2, int depth) {
  const int t = threadIdx.x;
  const int lane = t & 63, wid = t >> 6;
  const int wm = wid >> 1, wn = wid & 1;
  const int l15 = lane & 15, lg4 = lane >> 4;
  const int tok0 = blockIdx.x * 32;
  const int b = blockIdx.x >> 3;

  __shared__ __align__(16) ushort s_a[32][200];
  __shared__ __align__(16) ushort s_w[2][192][40];
  __shared__ __align__(16) ushort s_ff[32][200];
  __shared__ float s_red[32][4];

  uint4 pre[3];
  int cur = 0;
  auto LOADW = [&](const ushort* base, int stride, int ks) {
#pragma unroll
    for (int i = 0; i < 3; ++i) {
      const int idx = t + 256 * i;
      const int row = idx >> 2, c4 = (idx & 3) * 8;
      pre[i] = *(const uint4*)&base[row * stride + ks * 32 + c4];
    }
  };
  auto WRITEW = [&](int buf) {
#pragma unroll
    for (int i = 0; i < 3; ++i) {
      const int idx = t + 256 * i;
      const int row = idx >> 2, c4 = (idx & 3) * 8;
      *(uint4*)&s_w[buf][row][c4] = pre[i];
    }
  };
  // 6-step GEMM section with chained prefetch into the next section's tile 0.
  auto run6 = [&](f32x4* acc, const ushort (*Asrc)[200], const ushort* base,
                  int stride, const ushort* nxt, int nstride) {
#pragma unroll 1
    for (int ks = 0; ks < 6; ++ks) {
      const bool lastk = (ks == 5);
      const bool hn = !lastk || (nxt != nullptr);
      if (hn) LOADW(lastk ? nxt : base, lastk ? nstride : stride,
                    lastk ? 0 : ks + 1);
      const bf16x8 a = *(const bf16x8*)&Asrc[wm * 16 + l15][ks * 32 + 8 * lg4];
#pragma unroll
      for (int f = 0; f < 6; ++f) {
        const bf16x8 bb =
            *(const bf16x8*)&s_w[cur][wn * 96 + 16 * f + l15][8 * lg4];
        acc[f] = __builtin_amdgcn_mfma_f32_16x16x32_bf16(a, bb, acc[f], 0, 0, 0);
      }
      if (hn) WRITEW(cur ^ 1);
      __syncthreads();
      cur ^= 1;
    }
  };

  const ushort* kvb = kvT + (size_t)b * 36864;
  const ushort* f1b0 = f1T + depth * 73728;
  const ushort* f1b1 = f1b0 + 36864;
  const ushort* f2bb = f2T + depth * 73728;

  // prologue: stage qs -> s_a, o1 tile0 -> s_w[0], one barrier
  LOADW(kvb, 192, 0);
#pragma unroll
  for (int i = 0; i < 3; ++i) {
    const int idx = t + 256 * i;
    const int row = idx / 24, c8 = (idx % 24) * 8;
    *(uint4*)&s_a[row][c8] = *(const uint4*)&qs_bf[((size_t)tok0 + row) * 192 + c8];
  }
  WRITEW(0);
  __syncthreads();

  f32x4 o1[6];
#pragma unroll
  for (int f = 0; f < 6; ++f) o1[f] = (f32x4){0.f, 0.f, 0.f, 0.f};
  run6(o1, s_a, kvb, 192, f1b0, 192);

  // residual 1 + LN stats
  const float* g1p = g1 + depth * 192;
  const float* lw = lnw + depth * 192;
  const float* lb = lnb + depth * 192;
  const int rl = wm * 16 + 4 * lg4;
  float xbn[6][4];
  float psum[4] = {0.f, 0.f, 0.f, 0.f}, psq[4] = {0.f, 0.f, 0.f, 0.f};
#pragma unroll
  for (int f = 0; f < 6; ++f) {
    const int col = wn * 96 + 16 * f + l15;
#pragma unroll
    for (int reg = 0; reg < 4; ++reg) {
      const float xv =
          xb[((size_t)tok0 + rl + reg) * 192 + col] + o1[f][reg] * g1p[col];
      xbn[f][reg] = xv;
      psum[reg] += xv;
      psq[reg] = fmaf(xv, xv, psq[reg]);
    }
  }
#pragma unroll
  for (int reg = 0; reg < 4; ++reg) {
#pragma unroll
    for (int o = 8; o > 0; o >>= 1) {
      psum[reg] += __shfl_xor(psum[reg], o, 64);
      psq[reg] += __shfl_xor(psq[reg], o, 64);
    }
  }
  if (l15 == 0) {
#pragma unroll
    for (int reg = 0; reg < 4; ++reg) {
      s_red[rl + reg][wn] = psum[reg];
      s_red[rl + reg][2 + wn] = psq[reg];
    }
  }
  __syncthreads();
  float mean[4], inv[4];
#pragma unroll
  for (int reg = 0; reg < 4; ++reg) {
    const float s = s_red[rl + reg][0] + s_red[rl + reg][1];
    const float q = s_red[rl + reg][2] + s_red[rl + reg][3];
    mean[reg] = s * (1.f / 192.f);
    const float var = q * (1.f / 192.f) - mean[reg] * mean[reg];
    inv[reg] = rsqrtf(var + 1e-5f);
  }
#pragma unroll
  for (int f = 0; f < 6; ++f) {
    const int col = wn * 96 + 16 * f + l15;
#pragma unroll
    for (int reg = 0; reg < 4; ++reg)
      s_a[rl + reg][col] =
          f2bf((xbn[f][reg] - mean[reg]) * inv[reg] * lw[col] + lb[col]);
  }
  __syncthreads();

  // FFN
  f32x4 o2[6];
#pragma unroll
  for (int f = 0; f < 6; ++f) o2[f] = (f32x4){0.f, 0.f, 0.f, 0.f};

  // h = 0
  {
    f32x4 hh[6];
#pragma unroll
    for (int f = 0; f < 6; ++f) hh[f] = (f32x4){0.f, 0.f, 0.f, 0.f};
    run6(hh, s_a, f1b0, 192, f2bb, 384);
    const float* b1p = f1b + depth * 384;
#pragma unroll
    for (int f = 0; f < 6; ++f) {
      const int col = wn * 96 + 16 * f + l15;
#pragma unroll
      for (int reg = 0; reg < 4; ++reg)
        s_ff[rl + reg][col] = f2bf(gelu_f(hh[f][reg] + b1p[col]));
    }
    __syncthreads();
    run6(o2, s_ff, f2bb, 384, f1b1, 192);
  }
  // h = 1
  {
    f32x4 hh[6];
#pragma unroll
    for (int f = 0; f < 6; ++f) hh[f] = (f32x4){0.f, 0.f, 0.f, 0.f};
    run6(hh, s_a, f1b1, 192, f2bb + 192, 384);
    const float* b1p = f1b + depth * 384 + 192;
#pragma unroll
    for (int f = 0; f < 6; ++f) {
      const int col = wn * 96 + 16 * f + l15;
#pragma unroll
      for (int reg = 0; reg < 4; ++reg)
        s_ff[rl + reg][col] = f2bf(gelu_f(hh[f][reg] + b1p[col]));
    }
    __syncthreads();
    run6(o2, s_ff, f2bb + 192, 384, nullptr, 0);
  }

  const float* b2p = f2b + depth * 192;
  const float* g2p = g2 + depth * 192;
#pragma unroll
  for (int f = 0; f < 6; ++f) {
    const int col = wn * 96 + 16 * f + l15;
#pragma unroll
    for (int reg = 0; reg < 4; ++reg)
      xb[((size_t)tok0 + rl + reg) * 192 + col] =
          xbn[f][reg] + (o2[f][reg] + b2p[col]) * g2p[col];
  }
}

// ---------------------------------------------------------------------------
// K4: feat = LN(mean_n xb); out = feat @ head_w + head_b.
// ---------------------------------------------------------------------------
__global__ __launch_bounds__(192) void k4_head(
    const float* __restrict__ xb, const float* __restrict__ flnw,
    const float* __restrict__ flnb, const float* __restrict__ hw,
    const float* __restrict__ hb, float* __restrict__ out) {
  const int b = blockIdx.x, t = threadIdx.x;
  const int w = t >> 6, lane = t & 63;
  float s = 0.f;
  const float* base = xb + (size_t)b * 256 * 192 + t;
#pragma unroll 4
  for (int n = 0; n < 256; ++n) s += base[n * 192];
  const float feat_pre = s * (1.f / 256.f);
  __shared__ float red[3];
  __shared__ float feat[192];
  float sm = wsum64(feat_pre);
  if (lane == 0) red[w] = sm;
  __syncthreads();
  const float mean = (red[0] + red[1] + red[2]) * (1.f / 192.f);
  __syncthreads();
  const float dd = feat_pre - mean;
  sm = wsum64(dd * dd);
  if (lane == 0) red[w] = sm;
  __syncthreads();
  const float var = (red[0] + red[1] + red[2]) * (1.f / 192.f);
  feat[t] = dd * rsqrtf(var + 1e-5f) * flnw[t] + flnb[t];
  __syncthreads();
  if (t < 9) {
    float a = hb[t];
    for (int d = 0; d < 192; ++d) a = fmaf(feat[d], hw[d * 9 + t], a);
    out[b * 9 + t] = a;
  }
}

// ---------------------------------------------------------------------------
extern "C" void kernel_launch(void* const* d_in, const int* in_sizes, int n_in,
                              void* d_out, int out_size, void* d_ws, size_t ws_size,
                              hipStream_t stream) {
  (void)in_sizes; (void)n_in; (void)out_size; (void)ws_size;
  const float* x          = (const float*)d_in[0];
  const float* band_w     = (const float*)d_in[1];
  const float* band_b     = (const float*)d_in[2];
  const float* dw_w       = (const float*)d_in[3];
  const float* pw_w       = (const float*)d_in[4];
  const float* pe_ln_w    = (const float*)d_in[5];
  const float* pe_ln_b    = (const float*)d_in[6];
  const float* spec_proto = (const float*)d_in[7];
  const float* spat_proto = (const float*)d_in[8];
  const float* r1_w       = (const float*)d_in[9];
  const float* r1_b       = (const float*)d_in[10];
  const float* r2_w       = (const float*)d_in[11];
  const float* r2_b       = (const float*)d_in[12];
  const float* key_w      = (const float*)d_in[13];
  const float* pos_bias   = (const float*)d_in[14];
  const float* blk_ln_w   = (const float*)d_in[15];
  const float* blk_ln_b   = (const float*)d_in[16];
  const float* blk_q_w    = (const float*)d_in[17];
  const float* blk_v_w    = (const float*)d_in[18];
  const float* blk_f1_w   = (const float*)d_in[19];
  const float* blk_f1_b   = (const float*)d_in[20];
  const float* blk_f2_w   = (const float*)d_in[21];
  const float* blk_f2_b   = (const float*)d_in[22];
  const float* blk_g1     = (const float*)d_in[23];
  const float* blk_g2     = (const float*)d_in[24];
  const float* fin_ln_w   = (const float*)d_in[25];
  const float* fin_ln_b   = (const float*)d_in[26];
  const float* head_w     = (const float*)d_in[27];
  const float* head_b     = (const float*)d_in[28];

  float* ws    = (float*)d_ws;
  float* dw    = ws;                   //    65,536 f32
  float* xbuf  = dw + 65536;           // 1,572,864 f32
  float* bandT = xbuf + 1572864;       //     1,024 f32 (824 used)
  ushort* ush    = (ushort*)(bandT + 1024);
  ushort* qs_bf  = ush;                // 1,572,864
  ushort* kvT    = qs_bf + 1572864;    // 1,179,648
  ushort* keysT  = kvT + 1179648;      // 1,572,864
  ushort* vT     = keysT + 1572864;    // 1,572,864
  ushort* qwT    = vT + 1572864;       //   110,592
  ushort* vwT    = qwT + 110592;       //   110,592
  ushort* f1T    = vwT + 110592;       //   221,184
  ushort* f2T    = f1T + 221184;       //   221,184
  ushort* r1T    = f2T + 221184;       //    24,576
  ushort* r2T    = r1T + 24576;        //     6,144
  ushort* keyT   = r2T + 6144;         //    43,008

  prep_w<<<864, 256, 0, stream>>>(blk_q_w, blk_v_w, blk_f1_w, blk_f2_w,
                                  r1_w, r2_w, key_w, band_w,
                                  qwT, vwT, f1T, f2T, r1T, r2T, keyT, bandT);
  k1_band_dw<<<512, 512, 0, stream>>>(x, bandT, band_b, dw_w, dw);
  k2_mfma<<<256, 256, 0, stream>>>(dw, pw_w, pe_ln_w, pe_ln_b, spec_proto,
                                   spat_proto, r1T, r1_b, r2T, r2_b, keyT,
                                   pos_bias, xbuf, keysT);
  for (int d = 0; d < 3; ++d) {
    k3a_mfma<<<256, 256, 0, stream>>>(xbuf, blk_ln_w, blk_ln_b, qwT, vwT,
                                      qs_bf, vT, d);
    k3b_mfma<<<192, 256, 0, stream>>>(vT, keysT, kvT);
    k3c_mfma<<<256, 256, 0, stream>>>(xbuf, qs_bf, kvT, blk_ln_w, blk_ln_b,
                                      f1T, f2T, blk_f1_b, blk_f2_b, blk_g1,
                                      blk_g2, d);
  }
  k4_head<<<32, 192, 0, stream>>>(xbuf, fin_ln_w, fin_ln_b, head_w, head_b,
                                  (float*)d_out);
}

// Round 9
// 320.567 us; speedup vs baseline: 1.2491x; 1.2491x over previous
//
#include <hip/hip_runtime.h>
#include <math.h>

// ---------------------------------------------------------------------------
// OptimizedProtoHyperFormer — round 9: R6 base (full revert of R7/R8 changes)
// + k3 chain re-tiled to M=16 (k3a/k3c: 512 blocks, k3b: 384 blocks) for
// 2 blocks/CU TLP in the latency-bound regime.
// B=32, IB=103, H=W=256, P=16, RB=8, DIM=192, DEPTH=3, FFH=384, NT=8192.
// ---------------------------------------------------------------------------

typedef __attribute__((ext_vector_type(8))) short bf16x8;
typedef __attribute__((ext_vector_type(4))) float f32x4;

__device__ __forceinline__ float wsum64(float v) {
#pragma unroll
  for (int o = 32; o > 0; o >>= 1) v += __shfl_xor(v, o, 64);
  return v;
}
__device__ __forceinline__ float sum16(float v) {
#pragma unroll
  for (int o = 8; o > 0; o >>= 1) v += __shfl_xor(v, o, 64);
  return v;
}
__device__ __forceinline__ float max16(float v) {
#pragma unroll
  for (int o = 8; o > 0; o >>= 1) v = fmaxf(v, __shfl_xor(v, o, 64));
  return v;
}
__device__ __forceinline__ float gelu_f(float x) {
  return 0.5f * x * (1.0f + erff(x * 0.7071067811865476f));
}
__device__ __forceinline__ ushort f2bf(float f) {
  union { float f; unsigned u; } v;
  v.f = f;
  unsigned r = v.u + 0x7FFFu + ((v.u >> 16) & 1u);
  return (ushort)(r >> 16);
}

// ---------------------------------------------------------------------------
// prep: bf16 transposes of all MFMA weights + band_w transpose.
// ---------------------------------------------------------------------------
__global__ __launch_bounds__(256) void prep_w(
    const float* __restrict__ qw, const float* __restrict__ vw,
    const float* __restrict__ f1w, const float* __restrict__ f2w,
    const float* __restrict__ r1_w, const float* __restrict__ r2_w,
    const float* __restrict__ key_w, const float* __restrict__ band_w,
    ushort* __restrict__ qwT, ushort* __restrict__ vwT,
    ushort* __restrict__ f1T, ushort* __restrict__ f2T,
    ushort* __restrict__ r1T, ushort* __restrict__ r2T,
    ushort* __restrict__ keyT, float* __restrict__ bandT) {
  const int i = blockIdx.x * 256 + threadIdx.x;
  if (i < 110592) {  // qw, vw: [3][192][192] -> [3][j][k]
    const int d = i / 36864, r = i % 36864;
    const int k = r / 192, c = r % 192;
    qwT[d * 36864 + c * 192 + k] = f2bf(qw[i]);
    vwT[d * 36864 + c * 192 + k] = f2bf(vw[i]);
  }
  if (i < 221184) {
    const int d = i / 73728, r = i % 73728;
    const int k = r / 384, j = r % 384;        // f1: [3][192][384] -> [3][384][192]
    f1T[d * 73728 + j * 192 + k] = f2bf(f1w[i]);
    const int k2 = r / 192, j2 = r % 192;      // f2: [3][384][192] -> [3][192][384]
    f2T[d * 73728 + j2 * 384 + k2] = f2bf(f2w[i]);
  }
  if (i < 24576) {  // r1: [192][128] -> [j:128][k:192]
    const int j = i / 192, k = i % 192;
    r1T[i] = f2bf(r1_w[k * 128 + j]);
  }
  if (i < 6144) {   // r2: [128][48] -> [j:48][k:128]
    const int j = i / 128, k = i % 128;
    r2T[i] = f2bf(r2_w[k * 48 + j]);
  }
  if (i < 43008) {  // key: [200][192] -> [j:192][k:224 padded]
    const int j = i / 224, k = i % 224;
    keyT[i] = (k < 200) ? f2bf(key_w[k * 192 + j]) : (ushort)0;
  }
  if (i < 824) {    // band_w: [8][103] -> [103][8]
    const int ch = i >> 3, c = i & 7;
    bandT[i] = band_w[c * 103 + ch];
  }
}

// ---------------------------------------------------------------------------
// K1 (R6 version — HBM-bound winner): fused band-reduction + depthwise conv.
// ---------------------------------------------------------------------------
__global__ __launch_bounds__(512) void k1_band_dw(
    const float* __restrict__ x, const float* __restrict__ bandT,
    const float* __restrict__ band_b, const float* __restrict__ dw_w,
    float* __restrict__ dw_out) {
  const int blk = blockIdx.x;
  const int b = blk >> 4, ip = blk & 15;
  const int t = threadIdx.x;
  const int col4 = t & 63;
  const int j = col4 >> 2;
  const int qb = (col4 & 3) << 2;
  const int p0 = t >> 6;

  float acc[8][8];
#pragma unroll
  for (int e = 0; e < 8; ++e)
#pragma unroll
    for (int c = 0; c < 8; ++c) acc[e][c] = 0.f;

  const f32x4* xp = (const f32x4*)x + (size_t)b * (103 * 16384) + (size_t)ip * 1024;

  auto body = [&](const f32x4 v0, const f32x4 v1, const int ch) {
    const f32x4 wA = *(const f32x4*)&bandT[ch * 8];
    const f32x4 wB = *(const f32x4*)&bandT[ch * 8 + 4];
    const float bw[8] = {wA.x, wA.y, wA.z, wA.w, wB.x, wB.y, wB.z, wB.w};
#pragma unroll
    for (int c = 0; c < 8; ++c) {
      acc[0][c] = fmaf(v0.x, bw[c], acc[0][c]);
      acc[1][c] = fmaf(v0.y, bw[c], acc[1][c]);
      acc[2][c] = fmaf(v0.z, bw[c], acc[2][c]);
      acc[3][c] = fmaf(v0.w, bw[c], acc[3][c]);
      acc[4][c] = fmaf(v1.x, bw[c], acc[4][c]);
      acc[5][c] = fmaf(v1.y, bw[c], acc[5][c]);
      acc[6][c] = fmaf(v1.z, bw[c], acc[6][c]);
      acc[7][c] = fmaf(v1.w, bw[c], acc[7][c]);
    }
  };

  f32x4 p0v = __builtin_nontemporal_load(&xp[t]);
  f32x4 p1v = __builtin_nontemporal_load(&xp[t + 512]);
  f32x4 q0v = __builtin_nontemporal_load(&xp[t + 16384]);
  f32x4 q1v = __builtin_nontemporal_load(&xp[t + 16896]);
#pragma unroll 1
  for (int ch = 0; ch < 100; ch += 2) {
    const f32x4 r0 = __builtin_nontemporal_load(&xp[t + 2 * 16384]);
    const f32x4 r1 = __builtin_nontemporal_load(&xp[t + 2 * 16384 + 512]);
    const f32x4 s0 = __builtin_nontemporal_load(&xp[t + 3 * 16384]);
    const f32x4 s1 = __builtin_nontemporal_load(&xp[t + 3 * 16384 + 512]);
    body(p0v, p1v, ch);
    body(q0v, q1v, ch + 1);
    p0v = r0; p1v = r1; q0v = s0; q1v = s1;
    xp += 2 * 16384;
  }
  const f32x4 u0 = __builtin_nontemporal_load(&xp[t + 2 * 16384]);
  const f32x4 u1 = __builtin_nontemporal_load(&xp[t + 2 * 16384 + 512]);
  body(p0v, p1v, 100);
  body(q0v, q1v, 101);
  body(u0, u1, 102);

  float dwt[8];
#pragma unroll
  for (int c = 0; c < 8; ++c) dwt[c] = 0.f;
#pragma unroll
  for (int e = 0; e < 8; ++e) {
    const int pp = p0 + ((e >> 2) << 3);
    const int qq = qb + (e & 3);
#pragma unroll
    for (int c = 0; c < 8; ++c)
      dwt[c] = fmaf(dw_w[c * 256 + pp * 16 + qq], acc[e][c] + band_b[c], dwt[c]);
  }
#pragma unroll
  for (int c = 0; c < 8; ++c) {
    dwt[c] += __shfl_xor(dwt[c], 1, 64);
    dwt[c] += __shfl_xor(dwt[c], 2, 64);
  }
  __shared__ float part[8][16][8];
  if ((t & 3) == 0) {
#pragma unroll
    for (int c = 0; c < 8; ++c) part[t >> 6][j][c] = dwt[c];
  }
  __syncthreads();
  if (t < 128) {
    const int jj = t >> 3, c = t & 7;
    float s = 0.f;
#pragma unroll
    for (int w = 0; w < 8; ++w) s += part[w][jj][c];
    dw_out[(((size_t)b * 16 + ip) * 16 + jj) * 8 + c] = s;
  }
}

// ---------------------------------------------------------------------------
// K2 (MFMA): pw+LN -> router r1/r2 -> top2 -> proto mix -> keysT bf16.
// 32 tokens/block, 256 blocks, 4 waves. Unchanged from R6.
// ---------------------------------------------------------------------------
__global__ __launch_bounds__(256) void k2_mfma(
    const float* __restrict__ dw, const float* __restrict__ pw_w,
    const float* __restrict__ pe_ln_w, const float* __restrict__ pe_ln_b,
    const float* __restrict__ spec_proto, const float* __restrict__ spat_proto,
    const ushort* __restrict__ r1T, const float* __restrict__ r1_b,
    const ushort* __restrict__ r2T, const float* __restrict__ r2_b,
    const ushort* __restrict__ keyT, const float* __restrict__ pos_bias,
    float* __restrict__ xb_out, ushort* __restrict__ keysT) {
  const int t = threadIdx.x;
  const int lane = t & 63, wid = t >> 6;
  const int wm = wid >> 1, wn = wid & 1;
  const int l15 = lane & 15, lg4 = lane >> 4;
  const int tok0 = blockIdx.x * 32;
  const int rl = wm * 16 + 4 * lg4;
  const int b = blockIdx.x >> 3;
  const int n0 = (blockIdx.x & 7) * 32;

  __shared__ float dw8s[32][8];
  __shared__ __align__(16) ushort s_xn[32][200];
  __shared__ __align__(16) ushort s_w[192][40];
  __shared__ __align__(16) ushort s_h[32][200];
  __shared__ __align__(16) ushort s_mix[32][232];
  __shared__ float s_rl[32][48];
  __shared__ float topwS[32][4];
  __shared__ int   topiS[32][4];

  dw8s[t >> 3][t & 7] = dw[((size_t)tok0 + (t >> 3)) * 8 + (t & 7)];
  __syncthreads();

#pragma unroll
  for (int half = 0; half < 2; ++half) {
    const int tt = half * 16 + (t >> 4), lg = t & 15;
    float pre[12], sm = 0.f;
#pragma unroll
    for (int m = 0; m < 12; ++m) {
      const int d = lg + 16 * m;
      const f32x4 pa = *(const f32x4*)&pw_w[d * 8];
      const f32x4 pb = *(const f32x4*)&pw_w[d * 8 + 4];
      float p = pa.x * dw8s[tt][0] + pa.y * dw8s[tt][1] + pa.z * dw8s[tt][2] +
                pa.w * dw8s[tt][3] + pb.x * dw8s[tt][4] + pb.y * dw8s[tt][5] +
                pb.z * dw8s[tt][6] + pb.w * dw8s[tt][7];
      pre[m] = p;
      sm += p;
    }
    sm = sum16(sm);
    const float mean = sm * (1.f / 192.f);
    float vv = 0.f;
#pragma unroll
    for (int m = 0; m < 12; ++m) {
      const float d0 = pre[m] - mean;
      vv = fmaf(d0, d0, vv);
    }
    vv = sum16(vv);
    const float inv = rsqrtf(vv * (1.f / 192.f) + 1e-5f);
#pragma unroll
    for (int m = 0; m < 12; ++m) {
      const int d = lg + 16 * m;
      const float xv = (pre[m] - mean) * inv * pe_ln_w[d] + pe_ln_b[d];
      s_xn[tt][d] = f2bf(xv);
      xb_out[((size_t)tok0 + tt) * 192 + d] = xv;
    }
  }
  __syncthreads();

  {
    f32x4 hacc[4];
#pragma unroll
    for (int f = 0; f < 4; ++f) hacc[f] = (f32x4){0.f, 0.f, 0.f, 0.f};
#pragma unroll 1
    for (int ks = 0; ks < 6; ++ks) {
#pragma unroll
      for (int i = 0; i < 2; ++i) {
        const int lin = t + 256 * i;
        const int row = lin >> 2, c8 = (lin & 3) * 8;
        *(uint4*)&s_w[row][c8] = *(const uint4*)&r1T[row * 192 + ks * 32 + c8];
      }
      __syncthreads();
      const bf16x8 a = *(const bf16x8*)&s_xn[wm * 16 + l15][ks * 32 + 8 * lg4];
#pragma unroll
      for (int f = 0; f < 4; ++f) {
        const bf16x8 bb = *(const bf16x8*)&s_w[wn * 64 + 16 * f + l15][8 * lg4];
        hacc[f] = __builtin_amdgcn_mfma_f32_16x16x32_bf16(a, bb, hacc[f], 0, 0, 0);
      }
      __syncthreads();
    }
#pragma unroll
    for (int f = 0; f < 4; ++f) {
      const int col = wn * 64 + 16 * f + l15;
#pragma unroll
      for (int reg = 0; reg < 4; ++reg)
        s_h[rl + reg][col] = f2bf(gelu_f(hacc[f][reg] + r1_b[col]));
    }
  }
  __syncthreads();

  {
    f32x4 racc[2];
    racc[0] = (f32x4){0.f, 0.f, 0.f, 0.f};
    racc[1] = (f32x4){0.f, 0.f, 0.f, 0.f};
#pragma unroll 1
    for (int ks = 0; ks < 4; ++ks) {
      if (t < 192) {
        const int row = t >> 2, c8 = (t & 3) * 8;
        *(uint4*)&s_w[row][c8] = *(const uint4*)&r2T[row * 128 + ks * 32 + c8];
      }
      __syncthreads();
      const bf16x8 a = *(const bf16x8*)&s_h[wm * 16 + l15][ks * 32 + 8 * lg4];
      if (wn == 0) {
#pragma unroll
        for (int f = 0; f < 2; ++f) {
          const bf16x8 bb = *(const bf16x8*)&s_w[16 * f + l15][8 * lg4];
          racc[f] = __builtin_amdgcn_mfma_f32_16x16x32_bf16(a, bb, racc[f], 0, 0, 0);
        }
      } else {
        const bf16x8 bb = *(const bf16x8*)&s_w[32 + l15][8 * lg4];
        racc[0] = __builtin_amdgcn_mfma_f32_16x16x32_bf16(a, bb, racc[0], 0, 0, 0);
      }
      __syncthreads();
    }
    if (wn == 0) {
#pragma unroll
      for (int f = 0; f < 2; ++f) {
        const int col = 16 * f + l15;
#pragma unroll
        for (int reg = 0; reg < 4; ++reg)
          s_rl[rl + reg][col] = racc[f][reg] + r2_b[col];
      }
    } else {
      const int col = 32 + l15;
#pragma unroll
      for (int reg = 0; reg < 4; ++reg)
        s_rl[rl + reg][col] = racc[0][reg] + r2_b[col];
    }
  }
  __syncthreads();

  if (t < 64) {
    const int tt = t >> 1, half = t & 1;
    const float* base = &s_rl[tt][half * 24];
    float v0 = -1e30f, v1 = -1e30f;
    int i0 = 0, i1 = 0;
    for (int k = 0; k < 24; ++k) {
      const float vv = base[k];
      if (vv > v0) { v1 = v0; i1 = i0; v0 = vv; i0 = k; }
      else if (vv > v1) { v1 = vv; i1 = k; }
    }
    const float tau = (float)(0.07 + 1e-8);
    const float e1 = expf((v1 - v0) / tau);
    const float inv = 1.f / (1.f + e1);
    topwS[tt][half * 2] = inv;
    topwS[tt][half * 2 + 1] = e1 * inv;
    topiS[tt][half * 2] = i0;
    topiS[tt][half * 2 + 1] = i1;
  }
  __syncthreads();

#pragma unroll
  for (int r = 0; r < 28; ++r) {
    const int f = t + 256 * r;  // 32*224 = 7168 exact
    const int tok = f / 224, c = f % 224;
    float val = 0.f;
    if (c < 8) {
      val = topwS[tok][0] * spec_proto[topiS[tok][0] * 8 + c] +
            topwS[tok][1] * spec_proto[topiS[tok][1] * 8 + c];
    } else if (c < 200) {
      const int cc = c - 8;
      val = topwS[tok][2] * spat_proto[topiS[tok][2] * 192 + cc] +
            topwS[tok][3] * spat_proto[topiS[tok][3] * 192 + cc];
    }
    s_mix[tok][c] = f2bf(val);
  }
  __syncthreads();

  {
    f32x4 kacc[6];
#pragma unroll
    for (int f = 0; f < 6; ++f) kacc[f] = (f32x4){0.f, 0.f, 0.f, 0.f};
#pragma unroll 1
    for (int ks = 0; ks < 7; ++ks) {
#pragma unroll
      for (int i = 0; i < 3; ++i) {
        const int lin = t + 256 * i;
        const int row = lin >> 2, c8 = (lin & 3) * 8;
        *(uint4*)&s_w[row][c8] = *(const uint4*)&keyT[row * 224 + ks * 32 + c8];
      }
      __syncthreads();
      const bf16x8 a = *(const bf16x8*)&s_mix[wm * 16 + l15][ks * 32 + 8 * lg4];
#pragma unroll
      for (int f = 0; f < 6; ++f) {
        const bf16x8 bb = *(const bf16x8*)&s_w[wn * 96 + 16 * f + l15][8 * lg4];
        kacc[f] = __builtin_amdgcn_mfma_f32_16x16x32_bf16(a, bb, kacc[f], 0, 0, 0);
      }
      __syncthreads();
    }
#pragma unroll
    for (int f = 0; f < 6; ++f) {
      const int col = wn * 96 + 16 * f + l15;
#pragma unroll
      for (int reg = 0; reg < 4; ++reg)
        keysT[((size_t)b * 192 + col) * 256 + n0 + rl + reg] =
            f2bf(kacc[f][reg] + pos_bias[col]);
    }
  }
}

// ---------------------------------------------------------------------------
// K3a (MFMA, M=16): LN -> xn bf16; q,v; softmax(q); vT bf16.
// 16 tokens/block, 512 blocks (2/CU), 4 waves split N 4-ways.
// ---------------------------------------------------------------------------
__global__ __launch_bounds__(256) void k3a_mfma(
    const float* __restrict__ xb, const float* __restrict__ lnw,
    const float* __restrict__ lnb, const ushort* __restrict__ qwT,
    const ushort* __restrict__ vwT, ushort* __restrict__ qs_bf,
    ushort* __restrict__ vT, int depth) {
  const int t = threadIdx.x;
  const int lane = t & 63, wid = t >> 6;  // wid = N-quarter
  const int l15 = lane & 15, lg4 = lane >> 4;
  const int tok0 = blockIdx.x * 16;
  const int b = blockIdx.x >> 4;
  const int n0 = (blockIdx.x & 15) * 16;
  const int rl = 4 * lg4;

  __shared__ __align__(16) char smem[6400 + 15360 + 15360];
  ushort (*s_xn)[200] = (ushort(*)[200])smem;
  ushort (*s_wq)[40] = (ushort(*)[40])(smem + 6400);
  ushort (*s_wv)[40] = (ushort(*)[40])(smem + 6400 + 15360);
  float (*s_q)[196] = (float(*)[196])(smem + 6400);  // overlays s_wq (12544B)

  const float* lw = lnw + depth * 192;
  const float* lb = lnb + depth * 192;
  {
    const int tt = t >> 4;
    const int lg = t & 15;
    const float* xrow = xb + ((size_t)tok0 + tt) * 192;
    float vals[12], sm = 0.f;
#pragma unroll
    for (int m = 0; m < 12; ++m) {
      vals[m] = xrow[lg + 16 * m];
      sm += vals[m];
    }
    sm = sum16(sm);
    const float mean = sm * (1.f / 192.f);
    float vv = 0.f;
#pragma unroll
    for (int m = 0; m < 12; ++m) {
      const float d0 = vals[m] - mean;
      vv = fmaf(d0, d0, vv);
    }
    vv = sum16(vv);
    const float inv = rsqrtf(vv * (1.f / 192.f) + 1e-5f);
#pragma unroll
    for (int m = 0; m < 12; ++m) {
      const int d = lg + 16 * m;
      s_xn[tt][d] = f2bf((vals[m] - mean) * inv * lw[d] + lb[d]);
    }
  }
  __syncthreads();

  f32x4 aq[3], av[3];
#pragma unroll
  for (int f = 0; f < 3; ++f) {
    aq[f] = (f32x4){0.f, 0.f, 0.f, 0.f};
    av[f] = (f32x4){0.f, 0.f, 0.f, 0.f};
  }
  const ushort* qbase = qwT + depth * 36864;
  const ushort* vbase = vwT + depth * 36864;
#pragma unroll 1
  for (int ks = 0; ks < 6; ++ks) {
#pragma unroll
    for (int i = 0; i < 3; ++i) {
      const int idx = t + 256 * i;
      const int row = idx >> 2, c4 = (idx & 3) * 8;
      *(uint4*)&s_wq[row][c4] = *(const uint4*)&qbase[row * 192 + ks * 32 + c4];
      *(uint4*)&s_wv[row][c4] = *(const uint4*)&vbase[row * 192 + ks * 32 + c4];
    }
    __syncthreads();
    const bf16x8 a = *(const bf16x8*)&s_xn[l15][ks * 32 + 8 * lg4];
#pragma unroll
    for (int f = 0; f < 3; ++f) {
      const bf16x8 bq = *(const bf16x8*)&s_wq[wid * 48 + 16 * f + l15][8 * lg4];
      const bf16x8 bv = *(const bf16x8*)&s_wv[wid * 48 + 16 * f + l15][8 * lg4];
      aq[f] = __builtin_amdgcn_mfma_f32_16x16x32_bf16(a, bq, aq[f], 0, 0, 0);
      av[f] = __builtin_amdgcn_mfma_f32_16x16x32_bf16(a, bv, av[f], 0, 0, 0);
    }
    __syncthreads();
  }

#pragma unroll
  for (int f = 0; f < 3; ++f) {
    const int col = wid * 48 + 16 * f + l15;
#pragma unroll
    for (int reg = 0; reg < 4; ++reg) {
      vT[((size_t)b * 192 + col) * 256 + n0 + rl + reg] = f2bf(av[f][reg]);
      s_q[rl + reg][col] = aq[f][reg];
    }
  }
  __syncthreads();

  {
    const int tt = t >> 4;
    const int lg = t & 15;
    float vals[12], mx = -1e30f;
#pragma unroll
    for (int m = 0; m < 12; ++m) {
      vals[m] = s_q[tt][lg + 16 * m];
      mx = fmaxf(mx, vals[m]);
    }
    mx = max16(mx);
    float s = 0.f;
#pragma unroll
    for (int m = 0; m < 12; ++m) {
      vals[m] = expf(vals[m] - mx);
      s += vals[m];
    }
    s = sum16(s);
    const float inv = 1.f / s;
#pragma unroll
    for (int m = 0; m < 12; ++m)
      qs_bf[((size_t)tok0 + tt) * 192 + lg + 16 * m] = f2bf(vals[m] * inv);
  }
}

// ---------------------------------------------------------------------------
// K3b (MFMA, M=16): KV^T[b][d][c] = sum_n vT[b][d][n]*keysT[b][c][n], K=256.
// Grid: 32 batches x 12 d-tiles = 384 blocks, 4 waves split N 4-ways.
// ---------------------------------------------------------------------------
__global__ __launch_bounds__(256) void k3b_mfma(
    const ushort* __restrict__ vT, const ushort* __restrict__ keysT,
    ushort* __restrict__ kvT) {
  const int t = threadIdx.x;
  const int lane = t & 63, wid = t >> 6;
  const int l15 = lane & 15, lg4 = lane >> 4;
  const int b = blockIdx.x / 12;
  const int d0 = (blockIdx.x % 12) * 16;
  const int rl = 4 * lg4;

  __shared__ __align__(16) ushort s_a[16][264];  // vT tile: 16 x 256
  __shared__ __align__(16) ushort s_w[192][40];  // keysT stage

  const ushort* vbase = vT + ((size_t)b * 192 + d0) * 256;
#pragma unroll
  for (int i = 0; i < 2; ++i) {
    const int idx = t + 256 * i;
    const int row = idx >> 5, c8 = (idx & 31) * 8;
    *(uint4*)&s_a[row][c8] = *(const uint4*)&vbase[row * 256 + c8];
  }

  f32x4 acc[3];
#pragma unroll
  for (int f = 0; f < 3; ++f) acc[f] = (f32x4){0.f, 0.f, 0.f, 0.f};
  const ushort* kbase = keysT + (size_t)b * 192 * 256;
#pragma unroll 1
  for (int ks = 0; ks < 8; ++ks) {
#pragma unroll
    for (int i = 0; i < 3; ++i) {
      const int idx = t + 256 * i;
      const int row = idx >> 2, c4 = (idx & 3) * 8;
      *(uint4*)&s_w[row][c4] = *(const uint4*)&kbase[row * 256 + ks * 32 + c4];
    }
    __syncthreads();
    const bf16x8 a = *(const bf16x8*)&s_a[l15][ks * 32 + 8 * lg4];
#pragma unroll
    for (int f = 0; f < 3; ++f) {
      const bf16x8 bb = *(const bf16x8*)&s_w[wid * 48 + 16 * f + l15][8 * lg4];
      acc[f] = __builtin_amdgcn_mfma_f32_16x16x32_bf16(a, bb, acc[f], 0, 0, 0);
    }
    __syncthreads();
  }

#pragma unroll
  for (int f = 0; f < 3; ++f) {
    const int col = wid * 48 + 16 * f + l15;
#pragma unroll
    for (int reg = 0; reg < 4; ++reg)
      kvT[((size_t)b * 192 + d0 + rl + reg) * 192 + col] = f2bf(acc[f][reg]);
  }
}

// ---------------------------------------------------------------------------
// K3c (MFMA, M=16): o1 = qs@KV; residual; LN; FFN; residual.
// 16 tokens/block, 512 blocks (2/CU), 4 waves split N 4-ways.
// ---------------------------------------------------------------------------
__global__ __launch_bounds__(256) void k3c_mfma(
    float* __restrict__ xb, const ushort* __restrict__ qs_bf,
    const ushort* __restrict__ kvT, const float* __restrict__ lnw,
    const float* __restrict__ lnb, const ushort* __restrict__ f1T,
    const ushort* __restrict__ f2T, const float* __restrict__ f1b,
    const float* __restrict__ f2b, const float* __restrict__ g1,
    const float* __restrict__ g2, int depth) {
  const int t = threadIdx.x;
  const int lane = t & 63, wid = t >> 6;
  const int l15 = lane & 15, lg4 = lane >> 4;
  const int tok0 = blockIdx.x * 16;
  const int b = blockIdx.x >> 4;
  const int rl = 4 * lg4;

  __shared__ __align__(16) ushort s_a[16][200];
  __shared__ __align__(16) ushort s_w[192][40];
  __shared__ __align__(16) ushort s_ff[16][200];
  __shared__ float s_red[16][8];

  // stage qs tile (16x192 = 384 uint4)
#pragma unroll
  for (int i = 0; i < 2; ++i) {
    const int idx = t + 256 * i;
    if (idx < 384) {
      const int row = idx / 24, c8 = (idx % 24) * 8;
      *(uint4*)&s_a[row][c8] =
          *(const uint4*)&qs_bf[((size_t)tok0 + row) * 192 + c8];
    }
  }
  __syncthreads();

  f32x4 o1[3];
#pragma unroll
  for (int f = 0; f < 3; ++f) o1[f] = (f32x4){0.f, 0.f, 0.f, 0.f};
  const ushort* kvb = kvT + (size_t)b * 36864;
#pragma unroll 1
  for (int ks = 0; ks < 6; ++ks) {
#pragma unroll
    for (int i = 0; i < 3; ++i) {
      const int idx = t + 256 * i;
      const int row = idx >> 2, c4 = (idx & 3) * 8;
      *(uint4*)&s_w[row][c4] = *(const uint4*)&kvb[row * 192 + ks * 32 + c4];
    }
    __syncthreads();
    const bf16x8 a = *(const bf16x8*)&s_a[l15][ks * 32 + 8 * lg4];
#pragma unroll
    for (int f = 0; f < 3; ++f) {
      const bf16x8 bb = *(const bf16x8*)&s_w[wid * 48 + 16 * f + l15][8 * lg4];
      o1[f] = __builtin_amdgcn_mfma_f32_16x16x32_bf16(a, bb, o1[f], 0, 0, 0);
    }
    __syncthreads();
  }

  // residual 1 + LN stats
  const float* g1p = g1 + depth * 192;
  const float* lw = lnw + depth * 192;
  const float* lb = lnb + depth * 192;
  float xbn[3][4];
  float psum[4] = {0.f, 0.f, 0.f, 0.f}, psq[4] = {0.f, 0.f, 0.f, 0.f};
#pragma unroll
  for (int f = 0; f < 3; ++f) {
    const int col = wid * 48 + 16 * f + l15;
#pragma unroll
    for (int reg = 0; reg < 4; ++reg) {
      const float xv =
          xb[((size_t)tok0 + rl + reg) * 192 + col] + o1[f][reg] * g1p[col];
      xbn[f][reg] = xv;
      psum[reg] += xv;
      psq[reg] = fmaf(xv, xv, psq[reg]);
    }
  }
#pragma unroll
  for (int reg = 0; reg < 4; ++reg) {
#pragma unroll
    for (int o = 8; o > 0; o >>= 1) {
      psum[reg] += __shfl_xor(psum[reg], o, 64);
      psq[reg] += __shfl_xor(psq[reg], o, 64);
    }
  }
  if (l15 == 0) {
#pragma unroll
    for (int reg = 0; reg < 4; ++reg) {
      s_red[rl + reg][wid] = psum[reg];
      s_red[rl + reg][4 + wid] = psq[reg];
    }
  }
  __syncthreads();
  float mean[4], inv[4];
#pragma unroll
  for (int reg = 0; reg < 4; ++reg) {
    const float s = s_red[rl + reg][0] + s_red[rl + reg][1] +
                    s_red[rl + reg][2] + s_red[rl + reg][3];
    const float q = s_red[rl + reg][4] + s_red[rl + reg][5] +
                    s_red[rl + reg][6] + s_red[rl + reg][7];
    mean[reg] = s * (1.f / 192.f);
    const float var = q * (1.f / 192.f) - mean[reg] * mean[reg];
    inv[reg] = rsqrtf(var + 1e-5f);
  }
#pragma unroll
  for (int f = 0; f < 3; ++f) {
    const int col = wid * 48 + 16 * f + l15;
#pragma unroll
    for (int reg = 0; reg < 4; ++reg)
      s_a[rl + reg][col] =
          f2bf((xbn[f][reg] - mean[reg]) * inv[reg] * lw[col] + lb[col]);
  }
  __syncthreads();

  // FFN: two N-halves of f1, each followed by its f2 K-half
  f32x4 o2[3];
#pragma unroll
  for (int f = 0; f < 3; ++f) o2[f] = (f32x4){0.f, 0.f, 0.f, 0.f};
#pragma unroll 1
  for (int h = 0; h < 2; ++h) {
    f32x4 hh[3];
#pragma unroll
    for (int f = 0; f < 3; ++f) hh[f] = (f32x4){0.f, 0.f, 0.f, 0.f};
    const ushort* f1base = f1T + depth * 73728 + h * 36864;
#pragma unroll 1
    for (int ks = 0; ks < 6; ++ks) {
#pragma unroll
      for (int i = 0; i < 3; ++i) {
        const int idx = t + 256 * i;
        const int row = idx >> 2, c4 = (idx & 3) * 8;
        *(uint4*)&s_w[row][c4] = *(const uint4*)&f1base[row * 192 + ks * 32 + c4];
      }
      __syncthreads();
      const bf16x8 a = *(const bf16x8*)&s_a[l15][ks * 32 + 8 * lg4];
#pragma unroll
      for (int f = 0; f < 3; ++f) {
        const bf16x8 bb = *(const bf16x8*)&s_w[wid * 48 + 16 * f + l15][8 * lg4];
        hh[f] = __builtin_amdgcn_mfma_f32_16x16x32_bf16(a, bb, hh[f], 0, 0, 0);
      }
      __syncthreads();
    }
    const float* b1p = f1b + depth * 384 + h * 192;
#pragma unroll
    for (int f = 0; f < 3; ++f) {
      const int col = wid * 48 + 16 * f + l15;
#pragma unroll
      for (int reg = 0; reg < 4; ++reg)
        s_ff[rl + reg][col] = f2bf(gelu_f(hh[f][reg] + b1p[col]));
    }
    __syncthreads();
    const ushort* f2base = f2T + depth * 73728;
#pragma unroll 1
    for (int ks2 = 0; ks2 < 6; ++ks2) {
#pragma unroll
      for (int i = 0; i < 3; ++i) {
        const int idx = t + 256 * i;
        const int row = idx >> 2, c4 = (idx & 3) * 8;
        *(uint4*)&s_w[row][c4] =
            *(const uint4*)&f2base[row * 384 + h * 192 + ks2 * 32 + c4];
      }
      __syncthreads();
      const bf16x8 a = *(const bf16x8*)&s_ff[l15][ks2 * 32 + 8 * lg4];
#pragma unroll
      for (int f = 0; f < 3; ++f) {
        const bf16x8 bb = *(const bf16x8*)&s_w[wid * 48 + 16 * f + l15][8 * lg4];
        o2[f] = __builtin_amdgcn_mfma_f32_16x16x32_bf16(a, bb, o2[f], 0, 0, 0);
      }
      __syncthreads();
    }
  }

  const float* b2p = f2b + depth * 192;
  const float* g2p = g2 + depth * 192;
#pragma unroll
  for (int f = 0; f < 3; ++f) {
    const int col = wid * 48 + 16 * f + l15;
#pragma unroll
    for (int reg = 0; reg < 4; ++reg)
      xb[((size_t)tok0 + rl + reg) * 192 + col] =
          xbn[f][reg] + (o2[f][reg] + b2p[col]) * g2p[col];
  }
}

// ---------------------------------------------------------------------------
// K4: feat = LN(mean_n xb); out = feat @ head_w + head_b.
// ---------------------------------------------------------------------------
__global__ __launch_bounds__(192) void k4_head(
    const float* __restrict__ xb, const float* __restrict__ flnw,
    const float* __restrict__ flnb, const float* __restrict__ hw,
    const float* __restrict__ hb, float* __restrict__ out) {
  const int b = blockIdx.x, t = threadIdx.x;
  const int w = t >> 6, lane = t & 63;
  float s = 0.f;
  const float* base = xb + (size_t)b * 256 * 192 + t;
#pragma unroll 4
  for (int n = 0; n < 256; ++n) s += base[n * 192];
  const float feat_pre = s * (1.f / 256.f);
  __shared__ float red[3];
  __shared__ float feat[192];
  float sm = wsum64(feat_pre);
  if (lane == 0) red[w] = sm;
  __syncthreads();
  const float mean = (red[0] + red[1] + red[2]) * (1.f / 192.f);
  __syncthreads();
  const float dd = feat_pre - mean;
  sm = wsum64(dd * dd);
  if (lane == 0) red[w] = sm;
  __syncthreads();
  const float var = (red[0] + red[1] + red[2]) * (1.f / 192.f);
  feat[t] = dd * rsqrtf(var + 1e-5f) * flnw[t] + flnb[t];
  __syncthreads();
  if (t < 9) {
    float a = hb[t];
    for (int d = 0; d < 192; ++d) a = fmaf(feat[d], hw[d * 9 + t], a);
    out[b * 9 + t] = a;
  }
}

// ---------------------------------------------------------------------------
extern "C" void kernel_launch(void* const* d_in, const int* in_sizes, int n_in,
                              void* d_out, int out_size, void* d_ws, size_t ws_size,
                              hipStream_t stream) {
  (void)in_sizes; (void)n_in; (void)out_size; (void)ws_size;
  const float* x          = (const float*)d_in[0];
  const float* band_w     = (const float*)d_in[1];
  const float* band_b     = (const float*)d_in[2];
  const float* dw_w       = (const float*)d_in[3];
  const float* pw_w       = (const float*)d_in[4];
  const float* pe_ln_w    = (const float*)d_in[5];
  const float* pe_ln_b    = (const float*)d_in[6];
  const float* spec_proto = (const float*)d_in[7];
  const float* spat_proto = (const float*)d_in[8];
  const float* r1_w       = (const float*)d_in[9];
  const float* r1_b       = (const float*)d_in[10];
  const float* r2_w       = (const float*)d_in[11];
  const float* r2_b       = (const float*)d_in[12];
  const float* key_w      = (const float*)d_in[13];
  const float* pos_bias   = (const float*)d_in[14];
  const float* blk_ln_w   = (const float*)d_in[15];
  const float* blk_ln_b   = (const float*)d_in[16];
  const float* blk_q_w    = (const float*)d_in[17];
  const float* blk_v_w    = (const float*)d_in[18];
  const float* blk_f1_w   = (const float*)d_in[19];
  const float* blk_f1_b   = (const float*)d_in[20];
  const float* blk_f2_w   = (const float*)d_in[21];
  const float* blk_f2_b   = (const float*)d_in[22];
  const float* blk_g1     = (const float*)d_in[23];
  const float* blk_g2     = (const float*)d_in[24];
  const float* fin_ln_w   = (const float*)d_in[25];
  const float* fin_ln_b   = (const float*)d_in[26];
  const float* head_w     = (const float*)d_in[27];
  const float* head_b     = (const float*)d_in[28];

  float* ws    = (float*)d_ws;
  float* dw    = ws;                   //    65,536 f32
  float* xbuf  = dw + 65536;           // 1,572,864 f32
  float* bandT = xbuf + 1572864;       //     1,024 f32 (824 used)
  ushort* ush    = (ushort*)(bandT + 1024);
  ushort* qs_bf  = ush;                // 1,572,864
  ushort* kvT    = qs_bf + 1572864;    // 1,179,648
  ushort* keysT  = kvT + 1179648;      // 1,572,864
  ushort* vT     = keysT + 1572864;    // 1,572,864
  ushort* qwT    = vT + 1572864;       //   110,592
  ushort* vwT    = qwT + 110592;       //   110,592
  ushort* f1T    = vwT + 110592;       //   221,184
  ushort* f2T    = f1T + 221184;       //   221,184
  ushort* r1T    = f2T + 221184;       //    24,576
  ushort* r2T    = r1T + 24576;        //     6,144
  ushort* keyT   = r2T + 6144;         //    43,008

  prep_w<<<864, 256, 0, stream>>>(blk_q_w, blk_v_w, blk_f1_w, blk_f2_w,
                                  r1_w, r2_w, key_w, band_w,
                                  qwT, vwT, f1T, f2T, r1T, r2T, keyT, bandT);
  k1_band_dw<<<512, 512, 0, stream>>>(x, bandT, band_b, dw_w, dw);
  k2_mfma<<<256, 256, 0, stream>>>(dw, pw_w, pe_ln_w, pe_ln_b, spec_proto,
                                   spat_proto, r1T, r1_b, r2T, r2_b, keyT,
                                   pos_bias, xbuf, keysT);
  for (int d = 0; d < 3; ++d) {
    k3a_mfma<<<512, 256, 0, stream>>>(xbuf, blk_ln_w, blk_ln_b, qwT, vwT,
                                      qs_bf, vT, d);
    k3b_mfma<<<384, 256, 0, stream>>>(vT, keysT, kvT);
    k3c_mfma<<<512, 256, 0, stream>>>(xbuf, qs_bf, kvT, blk_ln_w, blk_ln_b,
                                      f1T, f2T, blk_f1_b, blk_f2_b, blk_g1,
                                      blk_g2, d);
  }
  k4_head<<<32, 192, 0, stream>>>(xbuf, fin_ln_w, fin_ln_b, head_w, head_b,
                                  (float*)d_out);
}

// Round 10
// 316.827 us; speedup vs baseline: 1.2639x; 1.0118x over previous
//
#include <hip/hip_runtime.h>
#include <math.h>

// ---------------------------------------------------------------------------
// OptimizedProtoHyperFormer — round 10: R9 base + k3c(d)+k3a(d+1) fusion
// (9 -> 7 dispatches in the depth chain; removes 2 xb round-trips).
// B=32, IB=103, H=W=256, P=16, RB=8, DIM=192, DEPTH=3, FFH=384, NT=8192.
// ---------------------------------------------------------------------------

typedef __attribute__((ext_vector_type(8))) short bf16x8;
typedef __attribute__((ext_vector_type(4))) float f32x4;

__device__ __forceinline__ float wsum64(float v) {
#pragma unroll
  for (int o = 32; o > 0; o >>= 1) v += __shfl_xor(v, o, 64);
  return v;
}
__device__ __forceinline__ float sum16(float v) {
#pragma unroll
  for (int o = 8; o > 0; o >>= 1) v += __shfl_xor(v, o, 64);
  return v;
}
__device__ __forceinline__ float max16(float v) {
#pragma unroll
  for (int o = 8; o > 0; o >>= 1) v = fmaxf(v, __shfl_xor(v, o, 64));
  return v;
}
__device__ __forceinline__ float gelu_f(float x) {
  return 0.5f * x * (1.0f + erff(x * 0.7071067811865476f));
}
__device__ __forceinline__ ushort f2bf(float f) {
  union { float f; unsigned u; } v;
  v.f = f;
  unsigned r = v.u + 0x7FFFu + ((v.u >> 16) & 1u);
  return (ushort)(r >> 16);
}

// ---------------------------------------------------------------------------
// prep: bf16 transposes of all MFMA weights + band_w transpose.
// ---------------------------------------------------------------------------
__global__ __launch_bounds__(256) void prep_w(
    const float* __restrict__ qw, const float* __restrict__ vw,
    const float* __restrict__ f1w, const float* __restrict__ f2w,
    const float* __restrict__ r1_w, const float* __restrict__ r2_w,
    const float* __restrict__ key_w, const float* __restrict__ band_w,
    ushort* __restrict__ qwT, ushort* __restrict__ vwT,
    ushort* __restrict__ f1T, ushort* __restrict__ f2T,
    ushort* __restrict__ r1T, ushort* __restrict__ r2T,
    ushort* __restrict__ keyT, float* __restrict__ bandT) {
  const int i = blockIdx.x * 256 + threadIdx.x;
  if (i < 110592) {
    const int d = i / 36864, r = i % 36864;
    const int k = r / 192, c = r % 192;
    qwT[d * 36864 + c * 192 + k] = f2bf(qw[i]);
    vwT[d * 36864 + c * 192 + k] = f2bf(vw[i]);
  }
  if (i < 221184) {
    const int d = i / 73728, r = i % 73728;
    const int k = r / 384, j = r % 384;
    f1T[d * 73728 + j * 192 + k] = f2bf(f1w[i]);
    const int k2 = r / 192, j2 = r % 192;
    f2T[d * 73728 + j2 * 384 + k2] = f2bf(f2w[i]);
  }
  if (i < 24576) {
    const int j = i / 192, k = i % 192;
    r1T[i] = f2bf(r1_w[k * 128 + j]);
  }
  if (i < 6144) {
    const int j = i / 128, k = i % 128;
    r2T[i] = f2bf(r2_w[k * 48 + j]);
  }
  if (i < 43008) {
    const int j = i / 224, k = i % 224;
    keyT[i] = (k < 200) ? f2bf(key_w[k * 192 + j]) : (ushort)0;
  }
  if (i < 824) {
    const int ch = i >> 3, c = i & 7;
    bandT[i] = band_w[c * 103 + ch];
  }
}

// ---------------------------------------------------------------------------
// K1 (R6 version — HBM-bound winner): fused band-reduction + depthwise conv.
// ---------------------------------------------------------------------------
__global__ __launch_bounds__(512) void k1_band_dw(
    const float* __restrict__ x, const float* __restrict__ bandT,
    const float* __restrict__ band_b, const float* __restrict__ dw_w,
    float* __restrict__ dw_out) {
  const int blk = blockIdx.x;
  const int b = blk >> 4, ip = blk & 15;
  const int t = threadIdx.x;
  const int col4 = t & 63;
  const int j = col4 >> 2;
  const int qb = (col4 & 3) << 2;
  const int p0 = t >> 6;

  float acc[8][8];
#pragma unroll
  for (int e = 0; e < 8; ++e)
#pragma unroll
    for (int c = 0; c < 8; ++c) acc[e][c] = 0.f;

  const f32x4* xp = (const f32x4*)x + (size_t)b * (103 * 16384) + (size_t)ip * 1024;

  auto body = [&](const f32x4 v0, const f32x4 v1, const int ch) {
    const f32x4 wA = *(const f32x4*)&bandT[ch * 8];
    const f32x4 wB = *(const f32x4*)&bandT[ch * 8 + 4];
    const float bw[8] = {wA.x, wA.y, wA.z, wA.w, wB.x, wB.y, wB.z, wB.w};
#pragma unroll
    for (int c = 0; c < 8; ++c) {
      acc[0][c] = fmaf(v0.x, bw[c], acc[0][c]);
      acc[1][c] = fmaf(v0.y, bw[c], acc[1][c]);
      acc[2][c] = fmaf(v0.z, bw[c], acc[2][c]);
      acc[3][c] = fmaf(v0.w, bw[c], acc[3][c]);
      acc[4][c] = fmaf(v1.x, bw[c], acc[4][c]);
      acc[5][c] = fmaf(v1.y, bw[c], acc[5][c]);
      acc[6][c] = fmaf(v1.z, bw[c], acc[6][c]);
      acc[7][c] = fmaf(v1.w, bw[c], acc[7][c]);
    }
  };

  f32x4 p0v = __builtin_nontemporal_load(&xp[t]);
  f32x4 p1v = __builtin_nontemporal_load(&xp[t + 512]);
  f32x4 q0v = __builtin_nontemporal_load(&xp[t + 16384]);
  f32x4 q1v = __builtin_nontemporal_load(&xp[t + 16896]);
#pragma unroll 1
  for (int ch = 0; ch < 100; ch += 2) {
    const f32x4 r0 = __builtin_nontemporal_load(&xp[t + 2 * 16384]);
    const f32x4 r1 = __builtin_nontemporal_load(&xp[t + 2 * 16384 + 512]);
    const f32x4 s0 = __builtin_nontemporal_load(&xp[t + 3 * 16384]);
    const f32x4 s1 = __builtin_nontemporal_load(&xp[t + 3 * 16384 + 512]);
    body(p0v, p1v, ch);
    body(q0v, q1v, ch + 1);
    p0v = r0; p1v = r1; q0v = s0; q1v = s1;
    xp += 2 * 16384;
  }
  const f32x4 u0 = __builtin_nontemporal_load(&xp[t + 2 * 16384]);
  const f32x4 u1 = __builtin_nontemporal_load(&xp[t + 2 * 16384 + 512]);
  body(p0v, p1v, 100);
  body(q0v, q1v, 101);
  body(u0, u1, 102);

  float dwt[8];
#pragma unroll
  for (int c = 0; c < 8; ++c) dwt[c] = 0.f;
#pragma unroll
  for (int e = 0; e < 8; ++e) {
    const int pp = p0 + ((e >> 2) << 3);
    const int qq = qb + (e & 3);
#pragma unroll
    for (int c = 0; c < 8; ++c)
      dwt[c] = fmaf(dw_w[c * 256 + pp * 16 + qq], acc[e][c] + band_b[c], dwt[c]);
  }
#pragma unroll
  for (int c = 0; c < 8; ++c) {
    dwt[c] += __shfl_xor(dwt[c], 1, 64);
    dwt[c] += __shfl_xor(dwt[c], 2, 64);
  }
  __shared__ float part[8][16][8];
  if ((t & 3) == 0) {
#pragma unroll
    for (int c = 0; c < 8; ++c) part[t >> 6][j][c] = dwt[c];
  }
  __syncthreads();
  if (t < 128) {
    const int jj = t >> 3, c = t & 7;
    float s = 0.f;
#pragma unroll
    for (int w = 0; w < 8; ++w) s += part[w][jj][c];
    dw_out[(((size_t)b * 16 + ip) * 16 + jj) * 8 + c] = s;
  }
}

// ---------------------------------------------------------------------------
// K2 (MFMA): pw+LN -> router r1/r2 -> top2 -> proto mix -> keysT bf16.
// ---------------------------------------------------------------------------
__global__ __launch_bounds__(256) void k2_mfma(
    const float* __restrict__ dw, const float* __restrict__ pw_w,
    const float* __restrict__ pe_ln_w, const float* __restrict__ pe_ln_b,
    const float* __restrict__ spec_proto, const float* __restrict__ spat_proto,
    const ushort* __restrict__ r1T, const float* __restrict__ r1_b,
    const ushort* __restrict__ r2T, const float* __restrict__ r2_b,
    const ushort* __restrict__ keyT, const float* __restrict__ pos_bias,
    float* __restrict__ xb_out, ushort* __restrict__ keysT) {
  const int t = threadIdx.x;
  const int lane = t & 63, wid = t >> 6;
  const int wm = wid >> 1, wn = wid & 1;
  const int l15 = lane & 15, lg4 = lane >> 4;
  const int tok0 = blockIdx.x * 32;
  const int rl = wm * 16 + 4 * lg4;
  const int b = blockIdx.x >> 3;
  const int n0 = (blockIdx.x & 7) * 32;

  __shared__ float dw8s[32][8];
  __shared__ __align__(16) ushort s_xn[32][200];
  __shared__ __align__(16) ushort s_w[192][40];
  __shared__ __align__(16) ushort s_h[32][200];
  __shared__ __align__(16) ushort s_mix[32][232];
  __shared__ float s_rl[32][48];
  __shared__ float topwS[32][4];
  __shared__ int   topiS[32][4];

  dw8s[t >> 3][t & 7] = dw[((size_t)tok0 + (t >> 3)) * 8 + (t & 7)];
  __syncthreads();

#pragma unroll
  for (int half = 0; half < 2; ++half) {
    const int tt = half * 16 + (t >> 4), lg = t & 15;
    float pre[12], sm = 0.f;
#pragma unroll
    for (int m = 0; m < 12; ++m) {
      const int d = lg + 16 * m;
      const f32x4 pa = *(const f32x4*)&pw_w[d * 8];
      const f32x4 pb = *(const f32x4*)&pw_w[d * 8 + 4];
      float p = pa.x * dw8s[tt][0] + pa.y * dw8s[tt][1] + pa.z * dw8s[tt][2] +
                pa.w * dw8s[tt][3] + pb.x * dw8s[tt][4] + pb.y * dw8s[tt][5] +
                pb.z * dw8s[tt][6] + pb.w * dw8s[tt][7];
      pre[m] = p;
      sm += p;
    }
    sm = sum16(sm);
    const float mean = sm * (1.f / 192.f);
    float vv = 0.f;
#pragma unroll
    for (int m = 0; m < 12; ++m) {
      const float d0 = pre[m] - mean;
      vv = fmaf(d0, d0, vv);
    }
    vv = sum16(vv);
    const float inv = rsqrtf(vv * (1.f / 192.f) + 1e-5f);
#pragma unroll
    for (int m = 0; m < 12; ++m) {
      const int d = lg + 16 * m;
      const float xv = (pre[m] - mean) * inv * pe_ln_w[d] + pe_ln_b[d];
      s_xn[tt][d] = f2bf(xv);
      xb_out[((size_t)tok0 + tt) * 192 + d] = xv;
    }
  }
  __syncthreads();

  {
    f32x4 hacc[4];
#pragma unroll
    for (int f = 0; f < 4; ++f) hacc[f] = (f32x4){0.f, 0.f, 0.f, 0.f};
#pragma unroll 1
    for (int ks = 0; ks < 6; ++ks) {
#pragma unroll
      for (int i = 0; i < 2; ++i) {
        const int lin = t + 256 * i;
        const int row = lin >> 2, c8 = (lin & 3) * 8;
        *(uint4*)&s_w[row][c8] = *(const uint4*)&r1T[row * 192 + ks * 32 + c8];
      }
      __syncthreads();
      const bf16x8 a = *(const bf16x8*)&s_xn[wm * 16 + l15][ks * 32 + 8 * lg4];
#pragma unroll
      for (int f = 0; f < 4; ++f) {
        const bf16x8 bb = *(const bf16x8*)&s_w[wn * 64 + 16 * f + l15][8 * lg4];
        hacc[f] = __builtin_amdgcn_mfma_f32_16x16x32_bf16(a, bb, hacc[f], 0, 0, 0);
      }
      __syncthreads();
    }
#pragma unroll
    for (int f = 0; f < 4; ++f) {
      const int col = wn * 64 + 16 * f + l15;
#pragma unroll
      for (int reg = 0; reg < 4; ++reg)
        s_h[rl + reg][col] = f2bf(gelu_f(hacc[f][reg] + r1_b[col]));
    }
  }
  __syncthreads();

  {
    f32x4 racc[2];
    racc[0] = (f32x4){0.f, 0.f, 0.f, 0.f};
    racc[1] = (f32x4){0.f, 0.f, 0.f, 0.f};
#pragma unroll 1
    for (int ks = 0; ks < 4; ++ks) {
      if (t < 192) {
        const int row = t >> 2, c8 = (t & 3) * 8;
        *(uint4*)&s_w[row][c8] = *(const uint4*)&r2T[row * 128 + ks * 32 + c8];
      }
      __syncthreads();
      const bf16x8 a = *(const bf16x8*)&s_h[wm * 16 + l15][ks * 32 + 8 * lg4];
      if (wn == 0) {
#pragma unroll
        for (int f = 0; f < 2; ++f) {
          const bf16x8 bb = *(const bf16x8*)&s_w[16 * f + l15][8 * lg4];
          racc[f] = __builtin_amdgcn_mfma_f32_16x16x32_bf16(a, bb, racc[f], 0, 0, 0);
        }
      } else {
        const bf16x8 bb = *(const bf16x8*)&s_w[32 + l15][8 * lg4];
        racc[0] = __builtin_amdgcn_mfma_f32_16x16x32_bf16(a, bb, racc[0], 0, 0, 0);
      }
      __syncthreads();
    }
    if (wn == 0) {
#pragma unroll
      for (int f = 0; f < 2; ++f) {
        const int col = 16 * f + l15;
#pragma unroll
        for (int reg = 0; reg < 4; ++reg)
          s_rl[rl + reg][col] = racc[f][reg] + r2_b[col];
      }
    } else {
      const int col = 32 + l15;
#pragma unroll
      for (int reg = 0; reg < 4; ++reg)
        s_rl[rl + reg][col] = racc[0][reg] + r2_b[col];
    }
  }
  __syncthreads();

  if (t < 64) {
    const int tt = t >> 1, half = t & 1;
    const float* base = &s_rl[tt][half * 24];
    float v0 = -1e30f, v1 = -1e30f;
    int i0 = 0, i1 = 0;
    for (int k = 0; k < 24; ++k) {
      const float vv = base[k];
      if (vv > v0) { v1 = v0; i1 = i0; v0 = vv; i0 = k; }
      else if (vv > v1) { v1 = vv; i1 = k; }
    }
    const float tau = (float)(0.07 + 1e-8);
    const float e1 = expf((v1 - v0) / tau);
    const float inv = 1.f / (1.f + e1);
    topwS[tt][half * 2] = inv;
    topwS[tt][half * 2 + 1] = e1 * inv;
    topiS[tt][half * 2] = i0;
    topiS[tt][half * 2 + 1] = i1;
  }
  __syncthreads();

#pragma unroll
  for (int r = 0; r < 28; ++r) {
    const int f = t + 256 * r;
    const int tok = f / 224, c = f % 224;
    float val = 0.f;
    if (c < 8) {
      val = topwS[tok][0] * spec_proto[topiS[tok][0] * 8 + c] +
            topwS[tok][1] * spec_proto[topiS[tok][1] * 8 + c];
    } else if (c < 200) {
      const int cc = c - 8;
      val = topwS[tok][2] * spat_proto[topiS[tok][2] * 192 + cc] +
            topwS[tok][3] * spat_proto[topiS[tok][3] * 192 + cc];
    }
    s_mix[tok][c] = f2bf(val);
  }
  __syncthreads();

  {
    f32x4 kacc[6];
#pragma unroll
    for (int f = 0; f < 6; ++f) kacc[f] = (f32x4){0.f, 0.f, 0.f, 0.f};
#pragma unroll 1
    for (int ks = 0; ks < 7; ++ks) {
#pragma unroll
      for (int i = 0; i < 3; ++i) {
        const int lin = t + 256 * i;
        const int row = lin >> 2, c8 = (lin & 3) * 8;
        *(uint4*)&s_w[row][c8] = *(const uint4*)&keyT[row * 224 + ks * 32 + c8];
      }
      __syncthreads();
      const bf16x8 a = *(const bf16x8*)&s_mix[wm * 16 + l15][ks * 32 + 8 * lg4];
#pragma unroll
      for (int f = 0; f < 6; ++f) {
        const bf16x8 bb = *(const bf16x8*)&s_w[wn * 96 + 16 * f + l15][8 * lg4];
        kacc[f] = __builtin_amdgcn_mfma_f32_16x16x32_bf16(a, bb, kacc[f], 0, 0, 0);
      }
      __syncthreads();
    }
#pragma unroll
    for (int f = 0; f < 6; ++f) {
      const int col = wn * 96 + 16 * f + l15;
#pragma unroll
      for (int reg = 0; reg < 4; ++reg)
        keysT[((size_t)b * 192 + col) * 256 + n0 + rl + reg] =
            f2bf(kacc[f][reg] + pos_bias[col]);
    }
  }
}

// ---------------------------------------------------------------------------
// K3a (MFMA, M=16): LN -> xn bf16; q,v; softmax(q); vT bf16. (depth 0 only)
// ---------------------------------------------------------------------------
__global__ __launch_bounds__(256) void k3a_mfma(
    const float* __restrict__ xb, const float* __restrict__ lnw,
    const float* __restrict__ lnb, const ushort* __restrict__ qwT,
    const ushort* __restrict__ vwT, ushort* __restrict__ qs_bf,
    ushort* __restrict__ vT, int depth) {
  const int t = threadIdx.x;
  const int lane = t & 63, wid = t >> 6;
  const int l15 = lane & 15, lg4 = lane >> 4;
  const int tok0 = blockIdx.x * 16;
  const int b = blockIdx.x >> 4;
  const int n0 = (blockIdx.x & 15) * 16;
  const int rl = 4 * lg4;

  __shared__ __align__(16) char smem[6400 + 15360 + 15360];
  ushort (*s_xn)[200] = (ushort(*)[200])smem;
  ushort (*s_wq)[40] = (ushort(*)[40])(smem + 6400);
  ushort (*s_wv)[40] = (ushort(*)[40])(smem + 6400 + 15360);
  float (*s_q)[196] = (float(*)[196])(smem + 6400);

  const float* lw = lnw + depth * 192;
  const float* lb = lnb + depth * 192;
  {
    const int tt = t >> 4;
    const int lg = t & 15;
    const float* xrow = xb + ((size_t)tok0 + tt) * 192;
    float vals[12], sm = 0.f;
#pragma unroll
    for (int m = 0; m < 12; ++m) {
      vals[m] = xrow[lg + 16 * m];
      sm += vals[m];
    }
    sm = sum16(sm);
    const float mean = sm * (1.f / 192.f);
    float vv = 0.f;
#pragma unroll
    for (int m = 0; m < 12; ++m) {
      const float d0 = vals[m] - mean;
      vv = fmaf(d0, d0, vv);
    }
    vv = sum16(vv);
    const float inv = rsqrtf(vv * (1.f / 192.f) + 1e-5f);
#pragma unroll
    for (int m = 0; m < 12; ++m) {
      const int d = lg + 16 * m;
      s_xn[tt][d] = f2bf((vals[m] - mean) * inv * lw[d] + lb[d]);
    }
  }
  __syncthreads();

  f32x4 aq[3], av[3];
#pragma unroll
  for (int f = 0; f < 3; ++f) {
    aq[f] = (f32x4){0.f, 0.f, 0.f, 0.f};
    av[f] = (f32x4){0.f, 0.f, 0.f, 0.f};
  }
  const ushort* qbase = qwT + depth * 36864;
  const ushort* vbase = vwT + depth * 36864;
#pragma unroll 1
  for (int ks = 0; ks < 6; ++ks) {
#pragma unroll
    for (int i = 0; i < 3; ++i) {
      const int idx = t + 256 * i;
      const int row = idx >> 2, c4 = (idx & 3) * 8;
      *(uint4*)&s_wq[row][c4] = *(const uint4*)&qbase[row * 192 + ks * 32 + c4];
      *(uint4*)&s_wv[row][c4] = *(const uint4*)&vbase[row * 192 + ks * 32 + c4];
    }
    __syncthreads();
    const bf16x8 a = *(const bf16x8*)&s_xn[l15][ks * 32 + 8 * lg4];
#pragma unroll
    for (int f = 0; f < 3; ++f) {
      const bf16x8 bq = *(const bf16x8*)&s_wq[wid * 48 + 16 * f + l15][8 * lg4];
      const bf16x8 bv = *(const bf16x8*)&s_wv[wid * 48 + 16 * f + l15][8 * lg4];
      aq[f] = __builtin_amdgcn_mfma_f32_16x16x32_bf16(a, bq, aq[f], 0, 0, 0);
      av[f] = __builtin_amdgcn_mfma_f32_16x16x32_bf16(a, bv, av[f], 0, 0, 0);
    }
    __syncthreads();
  }

#pragma unroll
  for (int f = 0; f < 3; ++f) {
    const int col = wid * 48 + 16 * f + l15;
#pragma unroll
    for (int reg = 0; reg < 4; ++reg) {
      vT[((size_t)b * 192 + col) * 256 + n0 + rl + reg] = f2bf(av[f][reg]);
      s_q[rl + reg][col] = aq[f][reg];
    }
  }
  __syncthreads();

  {
    const int tt = t >> 4;
    const int lg = t & 15;
    float vals[12], mx = -1e30f;
#pragma unroll
    for (int m = 0; m < 12; ++m) {
      vals[m] = s_q[tt][lg + 16 * m];
      mx = fmaxf(mx, vals[m]);
    }
    mx = max16(mx);
    float s = 0.f;
#pragma unroll
    for (int m = 0; m < 12; ++m) {
      vals[m] = expf(vals[m] - mx);
      s += vals[m];
    }
    s = sum16(s);
    const float inv = 1.f / s;
#pragma unroll
    for (int m = 0; m < 12; ++m)
      qs_bf[((size_t)tok0 + tt) * 192 + lg + 16 * m] = f2bf(vals[m] * inv);
  }
}

// ---------------------------------------------------------------------------
// K3b (MFMA, M=16): KV^T[b][d][c] = sum_n vT[b][d][n]*keysT[b][c][n], K=256.
// ---------------------------------------------------------------------------
__global__ __launch_bounds__(256) void k3b_mfma(
    const ushort* __restrict__ vT, const ushort* __restrict__ keysT,
    ushort* __restrict__ kvT) {
  const int t = threadIdx.x;
  const int lane = t & 63, wid = t >> 6;
  const int l15 = lane & 15, lg4 = lane >> 4;
  const int b = blockIdx.x / 12;
  const int d0 = (blockIdx.x % 12) * 16;
  const int rl = 4 * lg4;

  __shared__ __align__(16) ushort s_a[16][264];
  __shared__ __align__(16) ushort s_w[192][40];

  const ushort* vbase = vT + ((size_t)b * 192 + d0) * 256;
#pragma unroll
  for (int i = 0; i < 2; ++i) {
    const int idx = t + 256 * i;
    const int row = idx >> 5, c8 = (idx & 31) * 8;
    *(uint4*)&s_a[row][c8] = *(const uint4*)&vbase[row * 256 + c8];
  }

  f32x4 acc[3];
#pragma unroll
  for (int f = 0; f < 3; ++f) acc[f] = (f32x4){0.f, 0.f, 0.f, 0.f};
  const ushort* kbase = keysT + (size_t)b * 192 * 256;
#pragma unroll 1
  for (int ks = 0; ks < 8; ++ks) {
#pragma unroll
    for (int i = 0; i < 3; ++i) {
      const int idx = t + 256 * i;
      const int row = idx >> 2, c4 = (idx & 3) * 8;
      *(uint4*)&s_w[row][c4] = *(const uint4*)&kbase[row * 256 + ks * 32 + c4];
    }
    __syncthreads();
    const bf16x8 a = *(const bf16x8*)&s_a[l15][ks * 32 + 8 * lg4];
#pragma unroll
    for (int f = 0; f < 3; ++f) {
      const bf16x8 bb = *(const bf16x8*)&s_w[wid * 48 + 16 * f + l15][8 * lg4];
      acc[f] = __builtin_amdgcn_mfma_f32_16x16x32_bf16(a, bb, acc[f], 0, 0, 0);
    }
    __syncthreads();
  }

#pragma unroll
  for (int f = 0; f < 3; ++f) {
    const int col = wid * 48 + 16 * f + l15;
#pragma unroll
    for (int reg = 0; reg < 4; ++reg)
      kvT[((size_t)b * 192 + d0 + rl + reg) * 192 + col] = f2bf(acc[f][reg]);
  }
}

// ---------------------------------------------------------------------------
// K3ca (MFMA, M=16, fused): o1 = qs@KV; residual; LN; FFN; residual -> xb;
// then (if fuse_next) LN(blk_ln[d+1]) -> q,v -> softmax -> qs_bf/vT for d+1.
// 16 tokens/block, 512 blocks, 4 waves split N 4-ways.
// ---------------------------------------------------------------------------
__global__ __launch_bounds__(256) void k3ca_mfma(
    float* __restrict__ xb, ushort* __restrict__ qs_bf,
    const ushort* __restrict__ kvT, const float* __restrict__ lnw,
    const float* __restrict__ lnb, const ushort* __restrict__ f1T,
    const ushort* __restrict__ f2T, const float* __restrict__ f1b,
    const float* __restrict__ f2b, const float* __restrict__ g1,
    const float* __restrict__ g2, const ushort* __restrict__ qwT,
    const ushort* __restrict__ vwT, ushort* __restrict__ vT,
    int depth, int fuse_next) {
  const int t = threadIdx.x;
  const int lane = t & 63, wid = t >> 6;
  const int l15 = lane & 15, lg4 = lane >> 4;
  const int tok0 = blockIdx.x * 16;
  const int b = blockIdx.x >> 4;
  const int n0 = (blockIdx.x & 15) * 16;
  const int rl = 4 * lg4;

  __shared__ __align__(16) char smem[6400 + 15360 + 15360 + 6400 + 512];
  ushort (*s_a)[200] = (ushort(*)[200])smem;                       // qs/xn2/xn-next
  ushort (*s_w)[40] = (ushort(*)[40])(smem + 6400);                // B stage 1
  ushort (*s_w2)[40] = (ushort(*)[40])(smem + 6400 + 15360);       // B stage 2 (v)
  ushort (*s_ff)[200] = (ushort(*)[200])(smem + 6400 + 2 * 15360);
  float (*s_red)[8] = (float(*)[8])(smem + 6400 + 2 * 15360 + 6400);
  float (*s_q)[196] = (float(*)[196])(smem + 6400);                // overlays s_w

  // stage qs tile (16x192 = 384 uint4)
#pragma unroll
  for (int i = 0; i < 2; ++i) {
    const int idx = t + 256 * i;
    if (idx < 384) {
      const int row = idx / 24, c8 = (idx % 24) * 8;
      *(uint4*)&s_a[row][c8] =
          *(const uint4*)&qs_bf[((size_t)tok0 + row) * 192 + c8];
    }
  }
  __syncthreads();

  f32x4 o1[3];
#pragma unroll
  for (int f = 0; f < 3; ++f) o1[f] = (f32x4){0.f, 0.f, 0.f, 0.f};
  const ushort* kvb = kvT + (size_t)b * 36864;
#pragma unroll 1
  for (int ks = 0; ks < 6; ++ks) {
#pragma unroll
    for (int i = 0; i < 3; ++i) {
      const int idx = t + 256 * i;
      const int row = idx >> 2, c4 = (idx & 3) * 8;
      *(uint4*)&s_w[row][c4] = *(const uint4*)&kvb[row * 192 + ks * 32 + c4];
    }
    __syncthreads();
    const bf16x8 a = *(const bf16x8*)&s_a[l15][ks * 32 + 8 * lg4];
#pragma unroll
    for (int f = 0; f < 3; ++f) {
      const bf16x8 bb = *(const bf16x8*)&s_w[wid * 48 + 16 * f + l15][8 * lg4];
      o1[f] = __builtin_amdgcn_mfma_f32_16x16x32_bf16(a, bb, o1[f], 0, 0, 0);
    }
    __syncthreads();
  }

  // residual 1 + LN stats
  const float* g1p = g1 + depth * 192;
  const float* lw = lnw + depth * 192;
  const float* lb = lnb + depth * 192;
  float xbn[3][4];
  {
    float psum[4] = {0.f, 0.f, 0.f, 0.f}, psq[4] = {0.f, 0.f, 0.f, 0.f};
#pragma unroll
    for (int f = 0; f < 3; ++f) {
      const int col = wid * 48 + 16 * f + l15;
#pragma unroll
      for (int reg = 0; reg < 4; ++reg) {
        const float xv =
            xb[((size_t)tok0 + rl + reg) * 192 + col] + o1[f][reg] * g1p[col];
        xbn[f][reg] = xv;
        psum[reg] += xv;
        psq[reg] = fmaf(xv, xv, psq[reg]);
      }
    }
#pragma unroll
    for (int reg = 0; reg < 4; ++reg) {
#pragma unroll
      for (int o = 8; o > 0; o >>= 1) {
        psum[reg] += __shfl_xor(psum[reg], o, 64);
        psq[reg] += __shfl_xor(psq[reg], o, 64);
      }
    }
    if (l15 == 0) {
#pragma unroll
      for (int reg = 0; reg < 4; ++reg) {
        s_red[rl + reg][wid] = psum[reg];
        s_red[rl + reg][4 + wid] = psq[reg];
      }
    }
  }
  __syncthreads();
  {
    float mean[4], inv[4];
#pragma unroll
    for (int reg = 0; reg < 4; ++reg) {
      const float s = s_red[rl + reg][0] + s_red[rl + reg][1] +
                      s_red[rl + reg][2] + s_red[rl + reg][3];
      const float q = s_red[rl + reg][4] + s_red[rl + reg][5] +
                      s_red[rl + reg][6] + s_red[rl + reg][7];
      mean[reg] = s * (1.f / 192.f);
      const float var = q * (1.f / 192.f) - mean[reg] * mean[reg];
      inv[reg] = rsqrtf(var + 1e-5f);
    }
#pragma unroll
    for (int f = 0; f < 3; ++f) {
      const int col = wid * 48 + 16 * f + l15;
#pragma unroll
      for (int reg = 0; reg < 4; ++reg)
        s_a[rl + reg][col] =
            f2bf((xbn[f][reg] - mean[reg]) * inv[reg] * lw[col] + lb[col]);
    }
  }
  __syncthreads();

  // FFN: two N-halves of f1, each followed by its f2 K-half
  f32x4 o2[3];
#pragma unroll
  for (int f = 0; f < 3; ++f) o2[f] = (f32x4){0.f, 0.f, 0.f, 0.f};
#pragma unroll 1
  for (int h = 0; h < 2; ++h) {
    f32x4 hh[3];
#pragma unroll
    for (int f = 0; f < 3; ++f) hh[f] = (f32x4){0.f, 0.f, 0.f, 0.f};
    const ushort* f1base = f1T + depth * 73728 + h * 36864;
#pragma unroll 1
    for (int ks = 0; ks < 6; ++ks) {
#pragma unroll
      for (int i = 0; i < 3; ++i) {
        const int idx = t + 256 * i;
        const int row = idx >> 2, c4 = (idx & 3) * 8;
        *(uint4*)&s_w[row][c4] = *(const uint4*)&f1base[row * 192 + ks * 32 + c4];
      }
      __syncthreads();
      const bf16x8 a = *(const bf16x8*)&s_a[l15][ks * 32 + 8 * lg4];
#pragma unroll
      for (int f = 0; f < 3; ++f) {
        const bf16x8 bb = *(const bf16x8*)&s_w[wid * 48 + 16 * f + l15][8 * lg4];
        hh[f] = __builtin_amdgcn_mfma_f32_16x16x32_bf16(a, bb, hh[f], 0, 0, 0);
      }
      __syncthreads();
    }
    const float* b1p = f1b + depth * 384 + h * 192;
#pragma unroll
    for (int f = 0; f < 3; ++f) {
      const int col = wid * 48 + 16 * f + l15;
#pragma unroll
      for (int reg = 0; reg < 4; ++reg)
        s_ff[rl + reg][col] = f2bf(gelu_f(hh[f][reg] + b1p[col]));
    }
    __syncthreads();
    const ushort* f2base = f2T + depth * 73728;
#pragma unroll 1
    for (int ks2 = 0; ks2 < 6; ++ks2) {
#pragma unroll
      for (int i = 0; i < 3; ++i) {
        const int idx = t + 256 * i;
        const int row = idx >> 2, c4 = (idx & 3) * 8;
        *(uint4*)&s_w[row][c4] =
            *(const uint4*)&f2base[row * 384 + h * 192 + ks2 * 32 + c4];
      }
      __syncthreads();
      const bf16x8 a = *(const bf16x8*)&s_ff[l15][ks2 * 32 + 8 * lg4];
#pragma unroll
      for (int f = 0; f < 3; ++f) {
        const bf16x8 bb = *(const bf16x8*)&s_w[wid * 48 + 16 * f + l15][8 * lg4];
        o2[f] = __builtin_amdgcn_mfma_f32_16x16x32_bf16(a, bb, o2[f], 0, 0, 0);
      }
      __syncthreads();
    }
  }

  // final residual -> xfin, write xb
  const float* b2p = f2b + depth * 192;
  const float* g2p = g2 + depth * 192;
  float xfin[3][4];
#pragma unroll
  for (int f = 0; f < 3; ++f) {
    const int col = wid * 48 + 16 * f + l15;
#pragma unroll
    for (int reg = 0; reg < 4; ++reg) {
      xfin[f][reg] = xbn[f][reg] + (o2[f][reg] + b2p[col]) * g2p[col];
      xb[((size_t)tok0 + rl + reg) * 192 + col] = xfin[f][reg];
    }
  }

  if (!fuse_next) return;

  // ---- fused k3a for depth+1 ----
  {
    float psum[4] = {0.f, 0.f, 0.f, 0.f}, psq[4] = {0.f, 0.f, 0.f, 0.f};
#pragma unroll
    for (int f = 0; f < 3; ++f) {
#pragma unroll
      for (int reg = 0; reg < 4; ++reg) {
        psum[reg] += xfin[f][reg];
        psq[reg] = fmaf(xfin[f][reg], xfin[f][reg], psq[reg]);
      }
    }
#pragma unroll
    for (int reg = 0; reg < 4; ++reg) {
#pragma unroll
      for (int o = 8; o > 0; o >>= 1) {
        psum[reg] += __shfl_xor(psum[reg], o, 64);
        psq[reg] += __shfl_xor(psq[reg], o, 64);
      }
    }
    if (l15 == 0) {
#pragma unroll
      for (int reg = 0; reg < 4; ++reg) {
        s_red[rl + reg][wid] = psum[reg];
        s_red[rl + reg][4 + wid] = psq[reg];
      }
    }
  }
  __syncthreads();
  {
    const float* lw2 = lnw + (depth + 1) * 192;
    const float* lb2 = lnb + (depth + 1) * 192;
    float mean[4], inv[4];
#pragma unroll
    for (int reg = 0; reg < 4; ++reg) {
      const float s = s_red[rl + reg][0] + s_red[rl + reg][1] +
                      s_red[rl + reg][2] + s_red[rl + reg][3];
      const float q = s_red[rl + reg][4] + s_red[rl + reg][5] +
                      s_red[rl + reg][6] + s_red[rl + reg][7];
      mean[reg] = s * (1.f / 192.f);
      const float var = q * (1.f / 192.f) - mean[reg] * mean[reg];
      inv[reg] = rsqrtf(var + 1e-5f);
    }
#pragma unroll
    for (int f = 0; f < 3; ++f) {
      const int col = wid * 48 + 16 * f + l15;
#pragma unroll
      for (int reg = 0; reg < 4; ++reg)
        s_a[rl + reg][col] =
            f2bf((xfin[f][reg] - mean[reg]) * inv[reg] * lw2[col] + lb2[col]);
    }
  }
  __syncthreads();

  f32x4 aq[3], av[3];
#pragma unroll
  for (int f = 0; f < 3; ++f) {
    aq[f] = (f32x4){0.f, 0.f, 0.f, 0.f};
    av[f] = (f32x4){0.f, 0.f, 0.f, 0.f};
  }
  const ushort* qbase = qwT + (depth + 1) * 36864;
  const ushort* vbase = vwT + (depth + 1) * 36864;
#pragma unroll 1
  for (int ks = 0; ks < 6; ++ks) {
#pragma unroll
    for (int i = 0; i < 3; ++i) {
      const int idx = t + 256 * i;
      const int row = idx >> 2, c4 = (idx & 3) * 8;
      *(uint4*)&s_w[row][c4] = *(const uint4*)&qbase[row * 192 + ks * 32 + c4];
      *(uint4*)&s_w2[row][c4] = *(const uint4*)&vbase[row * 192 + ks * 32 + c4];
    }
    __syncthreads();
    const bf16x8 a = *(const bf16x8*)&s_a[l15][ks * 32 + 8 * lg4];
#pragma unroll
    for (int f = 0; f < 3; ++f) {
      const bf16x8 bq = *(const bf16x8*)&s_w[wid * 48 + 16 * f + l15][8 * lg4];
      const bf16x8 bv = *(const bf16x8*)&s_w2[wid * 48 + 16 * f + l15][8 * lg4];
      aq[f] = __builtin_amdgcn_mfma_f32_16x16x32_bf16(a, bq, aq[f], 0, 0, 0);
      av[f] = __builtin_amdgcn_mfma_f32_16x16x32_bf16(a, bv, av[f], 0, 0, 0);
    }
    __syncthreads();
  }

#pragma unroll
  for (int f = 0; f < 3; ++f) {
    const int col = wid * 48 + 16 * f + l15;
#pragma unroll
    for (int reg = 0; reg < 4; ++reg) {
      vT[((size_t)b * 192 + col) * 256 + n0 + rl + reg] = f2bf(av[f][reg]);
      s_q[rl + reg][col] = aq[f][reg];
    }
  }
  __syncthreads();

  {
    const int tt = t >> 4;
    const int lg = t & 15;
    float vals[12], mx = -1e30f;
#pragma unroll
    for (int m = 0; m < 12; ++m) {
      vals[m] = s_q[tt][lg + 16 * m];
      mx = fmaxf(mx, vals[m]);
    }
    mx = max16(mx);
    float s = 0.f;
#pragma unroll
    for (int m = 0; m < 12; ++m) {
      vals[m] = expf(vals[m] - mx);
      s += vals[m];
    }
    s = sum16(s);
    const float inv = 1.f / s;
#pragma unroll
    for (int m = 0; m < 12; ++m)
      qs_bf[((size_t)tok0 + tt) * 192 + lg + 16 * m] = f2bf(vals[m] * inv);
  }
}

// ---------------------------------------------------------------------------
// K4: feat = LN(mean_n xb); out = feat @ head_w + head_b.
// ---------------------------------------------------------------------------
__global__ __launch_bounds__(192) void k4_head(
    const float* __restrict__ xb, const float* __restrict__ flnw,
    const float* __restrict__ flnb, const float* __restrict__ hw,
    const float* __restrict__ hb, float* __restrict__ out) {
  const int b = blockIdx.x, t = threadIdx.x;
  const int w = t >> 6, lane = t & 63;
  float s = 0.f;
  const float* base = xb + (size_t)b * 256 * 192 + t;
#pragma unroll 4
  for (int n = 0; n < 256; ++n) s += base[n * 192];
  const float feat_pre = s * (1.f / 256.f);
  __shared__ float red[3];
  __shared__ float feat[192];
  float sm = wsum64(feat_pre);
  if (lane == 0) red[w] = sm;
  __syncthreads();
  const float mean = (red[0] + red[1] + red[2]) * (1.f / 192.f);
  __syncthreads();
  const float dd = feat_pre - mean;
  sm = wsum64(dd * dd);
  if (lane == 0) red[w] = sm;
  __syncthreads();
  const float var = (red[0] + red[1] + red[2]) * (1.f / 192.f);
  feat[t] = dd * rsqrtf(var + 1e-5f) * flnw[t] + flnb[t];
  __syncthreads();
  if (t < 9) {
    float a = hb[t];
    for (int d = 0; d < 192; ++d) a = fmaf(feat[d], hw[d * 9 + t], a);
    out[b * 9 + t] = a;
  }
}

// ---------------------------------------------------------------------------
extern "C" void kernel_launch(void* const* d_in, const int* in_sizes, int n_in,
                              void* d_out, int out_size, void* d_ws, size_t ws_size,
                              hipStream_t stream) {
  (void)in_sizes; (void)n_in; (void)out_size; (void)ws_size;
  const float* x          = (const float*)d_in[0];
  const float* band_w     = (const float*)d_in[1];
  const float* band_b     = (const float*)d_in[2];
  const float* dw_w       = (const float*)d_in[3];
  const float* pw_w       = (const float*)d_in[4];
  const float* pe_ln_w    = (const float*)d_in[5];
  const float* pe_ln_b    = (const float*)d_in[6];
  const float* spec_proto = (const float*)d_in[7];
  const float* spat_proto = (const float*)d_in[8];
  const float* r1_w       = (const float*)d_in[9];
  const float* r1_b       = (const float*)d_in[10];
  const float* r2_w       = (const float*)d_in[11];
  const float* r2_b       = (const float*)d_in[12];
  const float* key_w      = (const float*)d_in[13];
  const float* pos_bias   = (const float*)d_in[14];
  const float* blk_ln_w   = (const float*)d_in[15];
  const float* blk_ln_b   = (const float*)d_in[16];
  const float* blk_q_w    = (const float*)d_in[17];
  const float* blk_v_w    = (const float*)d_in[18];
  const float* blk_f1_w   = (const float*)d_in[19];
  const float* blk_f1_b   = (const float*)d_in[20];
  const float* blk_f2_w   = (const float*)d_in[21];
  const float* blk_f2_b   = (const float*)d_in[22];
  const float* blk_g1     = (const float*)d_in[23];
  const float* blk_g2     = (const float*)d_in[24];
  const float* fin_ln_w   = (const float*)d_in[25];
  const float* fin_ln_b   = (const float*)d_in[26];
  const float* head_w     = (const float*)d_in[27];
  const float* head_b     = (const float*)d_in[28];

  float* ws    = (float*)d_ws;
  float* dw    = ws;                   //    65,536 f32
  float* xbuf  = dw + 65536;           // 1,572,864 f32
  float* bandT = xbuf + 1572864;       //     1,024 f32 (824 used)
  ushort* ush    = (ushort*)(bandT + 1024);
  ushort* qs_bf  = ush;                // 1,572,864
  ushort* kvT    = qs_bf + 1572864;    // 1,179,648
  ushort* keysT  = kvT + 1179648;      // 1,572,864
  ushort* vT     = keysT + 1572864;    // 1,572,864
  ushort* qwT    = vT + 1572864;       //   110,592
  ushort* vwT    = qwT + 110592;       //   110,592
  ushort* f1T    = vwT + 110592;       //   221,184
  ushort* f2T    = f1T + 221184;       //   221,184
  ushort* r1T    = f2T + 221184;       //    24,576
  ushort* r2T    = r1T + 24576;        //     6,144
  ushort* keyT   = r2T + 6144;         //    43,008

  prep_w<<<864, 256, 0, stream>>>(blk_q_w, blk_v_w, blk_f1_w, blk_f2_w,
                                  r1_w, r2_w, key_w, band_w,
                                  qwT, vwT, f1T, f2T, r1T, r2T, keyT, bandT);
  k1_band_dw<<<512, 512, 0, stream>>>(x, bandT, band_b, dw_w, dw);
  k2_mfma<<<256, 256, 0, stream>>>(dw, pw_w, pe_ln_w, pe_ln_b, spec_proto,
                                   spat_proto, r1T, r1_b, r2T, r2_b, keyT,
                                   pos_bias, xbuf, keysT);
  k3a_mfma<<<512, 256, 0, stream>>>(xbuf, blk_ln_w, blk_ln_b, qwT, vwT,
                                    qs_bf, vT, 0);
  for (int d = 0; d < 3; ++d) {
    k3b_mfma<<<384, 256, 0, stream>>>(vT, keysT, kvT);
    k3ca_mfma<<<512, 256, 0, stream>>>(xbuf, qs_bf, kvT, blk_ln_w, blk_ln_b,
                                       f1T, f2T, blk_f1_b, blk_f2_b, blk_g1,
                                       blk_g2, qwT, vwT, vT, d, (d < 2) ? 1 : 0);
  }
  k4_head<<<32, 192, 0, stream>>>(xbuf, fin_ln_w, fin_ln_b, head_w, head_b,
                                  (float*)d_out);
}

// Round 11
// 313.720 us; speedup vs baseline: 1.2764x; 1.0099x over previous
//
#include <hip/hip_runtime.h>
#include <math.h>

// ---------------------------------------------------------------------------
// OptimizedProtoHyperFormer — round 11: R10 base + k3a(0) fused into K2 tail
// (removes the last standalone k3a dispatch; LDS overlays keep k2 <= 64 KB).
// B=32, IB=103, H=W=256, P=16, RB=8, DIM=192, DEPTH=3, FFH=384, NT=8192.
// ---------------------------------------------------------------------------

typedef __attribute__((ext_vector_type(8))) short bf16x8;
typedef __attribute__((ext_vector_type(4))) float f32x4;

__device__ __forceinline__ float wsum64(float v) {
#pragma unroll
  for (int o = 32; o > 0; o >>= 1) v += __shfl_xor(v, o, 64);
  return v;
}
__device__ __forceinline__ float sum16(float v) {
#pragma unroll
  for (int o = 8; o > 0; o >>= 1) v += __shfl_xor(v, o, 64);
  return v;
}
__device__ __forceinline__ float max16(float v) {
#pragma unroll
  for (int o = 8; o > 0; o >>= 1) v = fmaxf(v, __shfl_xor(v, o, 64));
  return v;
}
__device__ __forceinline__ float gelu_f(float x) {
  return 0.5f * x * (1.0f + erff(x * 0.7071067811865476f));
}
__device__ __forceinline__ ushort f2bf(float f) {
  union { float f; unsigned u; } v;
  v.f = f;
  unsigned r = v.u + 0x7FFFu + ((v.u >> 16) & 1u);
  return (ushort)(r >> 16);
}

// ---------------------------------------------------------------------------
// prep: bf16 transposes of all MFMA weights + band_w transpose.
// ---------------------------------------------------------------------------
__global__ __launch_bounds__(256) void prep_w(
    const float* __restrict__ qw, const float* __restrict__ vw,
    const float* __restrict__ f1w, const float* __restrict__ f2w,
    const float* __restrict__ r1_w, const float* __restrict__ r2_w,
    const float* __restrict__ key_w, const float* __restrict__ band_w,
    ushort* __restrict__ qwT, ushort* __restrict__ vwT,
    ushort* __restrict__ f1T, ushort* __restrict__ f2T,
    ushort* __restrict__ r1T, ushort* __restrict__ r2T,
    ushort* __restrict__ keyT, float* __restrict__ bandT) {
  const int i = blockIdx.x * 256 + threadIdx.x;
  if (i < 110592) {
    const int d = i / 36864, r = i % 36864;
    const int k = r / 192, c = r % 192;
    qwT[d * 36864 + c * 192 + k] = f2bf(qw[i]);
    vwT[d * 36864 + c * 192 + k] = f2bf(vw[i]);
  }
  if (i < 221184) {
    const int d = i / 73728, r = i % 73728;
    const int k = r / 384, j = r % 384;
    f1T[d * 73728 + j * 192 + k] = f2bf(f1w[i]);
    const int k2 = r / 192, j2 = r % 192;
    f2T[d * 73728 + j2 * 384 + k2] = f2bf(f2w[i]);
  }
  if (i < 24576) {
    const int j = i / 192, k = i % 192;
    r1T[i] = f2bf(r1_w[k * 128 + j]);
  }
  if (i < 6144) {
    const int j = i / 128, k = i % 128;
    r2T[i] = f2bf(r2_w[k * 48 + j]);
  }
  if (i < 43008) {
    const int j = i / 224, k = i % 224;
    keyT[i] = (k < 200) ? f2bf(key_w[k * 192 + j]) : (ushort)0;
  }
  if (i < 824) {
    const int ch = i >> 3, c = i & 7;
    bandT[i] = band_w[c * 103 + ch];
  }
}

// ---------------------------------------------------------------------------
// K1 (R6 version — HBM-bound winner): fused band-reduction + depthwise conv.
// ---------------------------------------------------------------------------
__global__ __launch_bounds__(512) void k1_band_dw(
    const float* __restrict__ x, const float* __restrict__ bandT,
    const float* __restrict__ band_b, const float* __restrict__ dw_w,
    float* __restrict__ dw_out) {
  const int blk = blockIdx.x;
  const int b = blk >> 4, ip = blk & 15;
  const int t = threadIdx.x;
  const int col4 = t & 63;
  const int j = col4 >> 2;
  const int qb = (col4 & 3) << 2;
  const int p0 = t >> 6;

  float acc[8][8];
#pragma unroll
  for (int e = 0; e < 8; ++e)
#pragma unroll
    for (int c = 0; c < 8; ++c) acc[e][c] = 0.f;

  const f32x4* xp = (const f32x4*)x + (size_t)b * (103 * 16384) + (size_t)ip * 1024;

  auto body = [&](const f32x4 v0, const f32x4 v1, const int ch) {
    const f32x4 wA = *(const f32x4*)&bandT[ch * 8];
    const f32x4 wB = *(const f32x4*)&bandT[ch * 8 + 4];
    const float bw[8] = {wA.x, wA.y, wA.z, wA.w, wB.x, wB.y, wB.z, wB.w};
#pragma unroll
    for (int c = 0; c < 8; ++c) {
      acc[0][c] = fmaf(v0.x, bw[c], acc[0][c]);
      acc[1][c] = fmaf(v0.y, bw[c], acc[1][c]);
      acc[2][c] = fmaf(v0.z, bw[c], acc[2][c]);
      acc[3][c] = fmaf(v0.w, bw[c], acc[3][c]);
      acc[4][c] = fmaf(v1.x, bw[c], acc[4][c]);
      acc[5][c] = fmaf(v1.y, bw[c], acc[5][c]);
      acc[6][c] = fmaf(v1.z, bw[c], acc[6][c]);
      acc[7][c] = fmaf(v1.w, bw[c], acc[7][c]);
    }
  };

  f32x4 p0v = __builtin_nontemporal_load(&xp[t]);
  f32x4 p1v = __builtin_nontemporal_load(&xp[t + 512]);
  f32x4 q0v = __builtin_nontemporal_load(&xp[t + 16384]);
  f32x4 q1v = __builtin_nontemporal_load(&xp[t + 16896]);
#pragma unroll 1
  for (int ch = 0; ch < 100; ch += 2) {
    const f32x4 r0 = __builtin_nontemporal_load(&xp[t + 2 * 16384]);
    const f32x4 r1 = __builtin_nontemporal_load(&xp[t + 2 * 16384 + 512]);
    const f32x4 s0 = __builtin_nontemporal_load(&xp[t + 3 * 16384]);
    const f32x4 s1 = __builtin_nontemporal_load(&xp[t + 3 * 16384 + 512]);
    body(p0v, p1v, ch);
    body(q0v, q1v, ch + 1);
    p0v = r0; p1v = r1; q0v = s0; q1v = s1;
    xp += 2 * 16384;
  }
  const f32x4 u0 = __builtin_nontemporal_load(&xp[t + 2 * 16384]);
  const f32x4 u1 = __builtin_nontemporal_load(&xp[t + 2 * 16384 + 512]);
  body(p0v, p1v, 100);
  body(q0v, q1v, 101);
  body(u0, u1, 102);

  float dwt[8];
#pragma unroll
  for (int c = 0; c < 8; ++c) dwt[c] = 0.f;
#pragma unroll
  for (int e = 0; e < 8; ++e) {
    const int pp = p0 + ((e >> 2) << 3);
    const int qq = qb + (e & 3);
#pragma unroll
    for (int c = 0; c < 8; ++c)
      dwt[c] = fmaf(dw_w[c * 256 + pp * 16 + qq], acc[e][c] + band_b[c], dwt[c]);
  }
#pragma unroll
  for (int c = 0; c < 8; ++c) {
    dwt[c] += __shfl_xor(dwt[c], 1, 64);
    dwt[c] += __shfl_xor(dwt[c], 2, 64);
  }
  __shared__ float part[8][16][8];
  if ((t & 3) == 0) {
#pragma unroll
    for (int c = 0; c < 8; ++c) part[t >> 6][j][c] = dwt[c];
  }
  __syncthreads();
  if (t < 128) {
    const int jj = t >> 3, c = t & 7;
    float s = 0.f;
#pragma unroll
    for (int w = 0; w < 8; ++w) s += part[w][jj][c];
    dw_out[(((size_t)b * 16 + ip) * 16 + jj) * 8 + c] = s;
  }
}

// ---------------------------------------------------------------------------
// K2 (MFMA, fused k3a depth-0 tail): pw+LN -> router -> keysT; then
// LN(blk_ln[0]) -> q,v -> softmax -> qs_bf / vT for depth 0.
// 32 tokens/block, 256 blocks, 4 waves. Static LDS 64,000 B with overlays.
// ---------------------------------------------------------------------------
__global__ __launch_bounds__(256) void k2_mfma(
    const float* __restrict__ dw, const float* __restrict__ pw_w,
    const float* __restrict__ pe_ln_w, const float* __restrict__ pe_ln_b,
    const float* __restrict__ spec_proto, const float* __restrict__ spat_proto,
    const ushort* __restrict__ r1T, const float* __restrict__ r1_b,
    const ushort* __restrict__ r2T, const float* __restrict__ r2_b,
    const ushort* __restrict__ keyT, const float* __restrict__ pos_bias,
    const float* __restrict__ blk_lnw, const float* __restrict__ blk_lnb,
    const ushort* __restrict__ qwT, const ushort* __restrict__ vwT,
    float* __restrict__ xb_out, ushort* __restrict__ keysT,
    ushort* __restrict__ qs_bf, ushort* __restrict__ vT) {
  const int t = threadIdx.x;
  const int lane = t & 63, wid = t >> 6;
  const int wm = wid >> 1, wn = wid & 1;
  const int l15 = lane & 15, lg4 = lane >> 4;
  const int tok0 = blockIdx.x * 32;
  const int rl = wm * 16 + 4 * lg4;
  const int b = blockIdx.x >> 3;
  const int n0 = (blockIdx.x & 7) * 32;

  __shared__ __align__(16) char smem[64000];
  float (*dw8s)[8]   = (float(*)[8])smem;                  // 0     .. 1024
  ushort (*s_xn)[200] = (ushort(*)[200])(smem + 1024);     // 1024  .. 13824
  ushort (*s_w)[40]   = (ushort(*)[40])(smem + 13824);     // 13824 .. 29184
  ushort (*s_h)[200]  = (ushort(*)[200])(smem + 29184);    // 29184 .. 41984
  ushort (*s_mix)[232] = (ushort(*)[232])(smem + 41984);   // 41984 .. 56832
  float (*s_rl)[48]  = (float(*)[48])(smem + 56832);       // 56832 .. 62976
  float (*topwS)[4]  = (float(*)[4])(smem + 62976);        // 62976 .. 63488
  int (*topiS)[4]    = (int(*)[4])(smem + 63488);          // 63488 .. 64000
  // tail overlays (router buffers dead by then):
  ushort (*s_xn0)[200] = (ushort(*)[200])(smem + 1024);    // over s_xn
  ushort (*s_wq)[40]  = (ushort(*)[40])(smem + 13824);     // over s_w
  ushort (*s_wv)[40]  = (ushort(*)[40])(smem + 29184);     // over s_h/s_mix
  float (*s_q)[196]  = (float(*)[196])(smem + 13824);      // over s_wq/s_wv

  dw8s[t >> 3][t & 7] = dw[((size_t)tok0 + (t >> 3)) * 8 + (t & 7)];
  __syncthreads();

  // ---- phase 1: pw + LN -> xb fp32, s_xn bf16 ----
#pragma unroll
  for (int half = 0; half < 2; ++half) {
    const int tt = half * 16 + (t >> 4), lg = t & 15;
    float pre[12], sm = 0.f;
#pragma unroll
    for (int m = 0; m < 12; ++m) {
      const int d = lg + 16 * m;
      const f32x4 pa = *(const f32x4*)&pw_w[d * 8];
      const f32x4 pb = *(const f32x4*)&pw_w[d * 8 + 4];
      float p = pa.x * dw8s[tt][0] + pa.y * dw8s[tt][1] + pa.z * dw8s[tt][2] +
                pa.w * dw8s[tt][3] + pb.x * dw8s[tt][4] + pb.y * dw8s[tt][5] +
                pb.z * dw8s[tt][6] + pb.w * dw8s[tt][7];
      pre[m] = p;
      sm += p;
    }
    sm = sum16(sm);
    const float mean = sm * (1.f / 192.f);
    float vv = 0.f;
#pragma unroll
    for (int m = 0; m < 12; ++m) {
      const float d0 = pre[m] - mean;
      vv = fmaf(d0, d0, vv);
    }
    vv = sum16(vv);
    const float inv = rsqrtf(vv * (1.f / 192.f) + 1e-5f);
#pragma unroll
    for (int m = 0; m < 12; ++m) {
      const int d = lg + 16 * m;
      const float xv = (pre[m] - mean) * inv * pe_ln_w[d] + pe_ln_b[d];
      s_xn[tt][d] = f2bf(xv);
      xb_out[((size_t)tok0 + tt) * 192 + d] = xv;
    }
  }
  __syncthreads();

  // ---- phase 2: r1 (K=192 -> 128) + gelu -> s_h bf16 ----
  {
    f32x4 hacc[4];
#pragma unroll
    for (int f = 0; f < 4; ++f) hacc[f] = (f32x4){0.f, 0.f, 0.f, 0.f};
#pragma unroll 1
    for (int ks = 0; ks < 6; ++ks) {
#pragma unroll
      for (int i = 0; i < 2; ++i) {
        const int lin = t + 256 * i;
        const int row = lin >> 2, c8 = (lin & 3) * 8;
        *(uint4*)&s_w[row][c8] = *(const uint4*)&r1T[row * 192 + ks * 32 + c8];
      }
      __syncthreads();
      const bf16x8 a = *(const bf16x8*)&s_xn[wm * 16 + l15][ks * 32 + 8 * lg4];
#pragma unroll
      for (int f = 0; f < 4; ++f) {
        const bf16x8 bb = *(const bf16x8*)&s_w[wn * 64 + 16 * f + l15][8 * lg4];
        hacc[f] = __builtin_amdgcn_mfma_f32_16x16x32_bf16(a, bb, hacc[f], 0, 0, 0);
      }
      __syncthreads();
    }
#pragma unroll
    for (int f = 0; f < 4; ++f) {
      const int col = wn * 64 + 16 * f + l15;
#pragma unroll
      for (int reg = 0; reg < 4; ++reg)
        s_h[rl + reg][col] = f2bf(gelu_f(hacc[f][reg] + r1_b[col]));
    }
  }
  __syncthreads();

  // ---- phase 3: r2 (K=128 -> 48) -> s_rl fp32 ----
  {
    f32x4 racc[2];
    racc[0] = (f32x4){0.f, 0.f, 0.f, 0.f};
    racc[1] = (f32x4){0.f, 0.f, 0.f, 0.f};
#pragma unroll 1
    for (int ks = 0; ks < 4; ++ks) {
      if (t < 192) {
        const int row = t >> 2, c8 = (t & 3) * 8;
        *(uint4*)&s_w[row][c8] = *(const uint4*)&r2T[row * 128 + ks * 32 + c8];
      }
      __syncthreads();
      const bf16x8 a = *(const bf16x8*)&s_h[wm * 16 + l15][ks * 32 + 8 * lg4];
      if (wn == 0) {
#pragma unroll
        for (int f = 0; f < 2; ++f) {
          const bf16x8 bb = *(const bf16x8*)&s_w[16 * f + l15][8 * lg4];
          racc[f] = __builtin_amdgcn_mfma_f32_16x16x32_bf16(a, bb, racc[f], 0, 0, 0);
        }
      } else {
        const bf16x8 bb = *(const bf16x8*)&s_w[32 + l15][8 * lg4];
        racc[0] = __builtin_amdgcn_mfma_f32_16x16x32_bf16(a, bb, racc[0], 0, 0, 0);
      }
      __syncthreads();
    }
    if (wn == 0) {
#pragma unroll
      for (int f = 0; f < 2; ++f) {
        const int col = 16 * f + l15;
#pragma unroll
        for (int reg = 0; reg < 4; ++reg)
          s_rl[rl + reg][col] = racc[f][reg] + r2_b[col];
      }
    } else {
      const int col = 32 + l15;
#pragma unroll
      for (int reg = 0; reg < 4; ++reg)
        s_rl[rl + reg][col] = racc[0][reg] + r2_b[col];
    }
  }
  __syncthreads();

  // ---- phase 4: top-2 + tau softmax (fp32) ----
  if (t < 64) {
    const int tt = t >> 1, half = t & 1;
    const float* base = &s_rl[tt][half * 24];
    float v0 = -1e30f, v1 = -1e30f;
    int i0 = 0, i1 = 0;
    for (int k = 0; k < 24; ++k) {
      const float vv = base[k];
      if (vv > v0) { v1 = v0; i1 = i0; v0 = vv; i0 = k; }
      else if (vv > v1) { v1 = vv; i1 = k; }
    }
    const float tau = (float)(0.07 + 1e-8);
    const float e1 = expf((v1 - v0) / tau);
    const float inv = 1.f / (1.f + e1);
    topwS[tt][half * 2] = inv;
    topwS[tt][half * 2 + 1] = e1 * inv;
    topiS[tt][half * 2] = i0;
    topiS[tt][half * 2 + 1] = i1;
  }
  __syncthreads();

  // ---- phase 5: mixed prototypes s_mix[32][224 padded] bf16 ----
#pragma unroll
  for (int r = 0; r < 28; ++r) {
    const int f = t + 256 * r;
    const int tok = f / 224, c = f % 224;
    float val = 0.f;
    if (c < 8) {
      val = topwS[tok][0] * spec_proto[topiS[tok][0] * 8 + c] +
            topwS[tok][1] * spec_proto[topiS[tok][1] * 8 + c];
    } else if (c < 200) {
      const int cc = c - 8;
      val = topwS[tok][2] * spat_proto[topiS[tok][2] * 192 + cc] +
            topwS[tok][3] * spat_proto[topiS[tok][3] * 192 + cc];
    }
    s_mix[tok][c] = f2bf(val);
  }
  __syncthreads();

  // ---- phase 6: keys (K=224 -> 192) + pos_bias -> keysT[b][c][n] bf16 ----
  {
    f32x4 kacc[6];
#pragma unroll
    for (int f = 0; f < 6; ++f) kacc[f] = (f32x4){0.f, 0.f, 0.f, 0.f};
#pragma unroll 1
    for (int ks = 0; ks < 7; ++ks) {
#pragma unroll
      for (int i = 0; i < 3; ++i) {
        const int lin = t + 256 * i;
        const int row = lin >> 2, c8 = (lin & 3) * 8;
        *(uint4*)&s_w[row][c8] = *(const uint4*)&keyT[row * 224 + ks * 32 + c8];
      }
      __syncthreads();
      const bf16x8 a = *(const bf16x8*)&s_mix[wm * 16 + l15][ks * 32 + 8 * lg4];
#pragma unroll
      for (int f = 0; f < 6; ++f) {
        const bf16x8 bb = *(const bf16x8*)&s_w[wn * 96 + 16 * f + l15][8 * lg4];
        kacc[f] = __builtin_amdgcn_mfma_f32_16x16x32_bf16(a, bb, kacc[f], 0, 0, 0);
      }
      __syncthreads();
    }
#pragma unroll
    for (int f = 0; f < 6; ++f) {
      const int col = wn * 96 + 16 * f + l15;
#pragma unroll
      for (int reg = 0; reg < 4; ++reg)
        keysT[((size_t)b * 192 + col) * 256 + n0 + rl + reg] =
            f2bf(kacc[f][reg] + pos_bias[col]);
    }
  }

  // ================= fused k3a (depth 0) tail =================
  // LN(blk_ln[0]) on xb (reload; L2-hot) -> s_xn0 bf16
#pragma unroll
  for (int half = 0; half < 2; ++half) {
    const int tt = half * 16 + (t >> 4);
    const int lg = t & 15;
    const float* xrow = xb_out + ((size_t)tok0 + tt) * 192;
    float vals[12], sm = 0.f;
#pragma unroll
    for (int m = 0; m < 12; ++m) {
      vals[m] = xrow[lg + 16 * m];
      sm += vals[m];
    }
    sm = sum16(sm);
    const float mean = sm * (1.f / 192.f);
    float vv = 0.f;
#pragma unroll
    for (int m = 0; m < 12; ++m) {
      const float d0 = vals[m] - mean;
      vv = fmaf(d0, d0, vv);
    }
    vv = sum16(vv);
    const float inv = rsqrtf(vv * (1.f / 192.f) + 1e-5f);
#pragma unroll
    for (int m = 0; m < 12; ++m) {
      const int d = lg + 16 * m;
      s_xn0[tt][d] = f2bf((vals[m] - mean) * inv * blk_lnw[d] + blk_lnb[d]);
    }
  }
  __syncthreads();

  f32x4 aq[6], av[6];
#pragma unroll
  for (int f = 0; f < 6; ++f) {
    aq[f] = (f32x4){0.f, 0.f, 0.f, 0.f};
    av[f] = (f32x4){0.f, 0.f, 0.f, 0.f};
  }
#pragma unroll 1
  for (int ks = 0; ks < 6; ++ks) {
#pragma unroll
    for (int i = 0; i < 3; ++i) {
      const int idx = t + 256 * i;
      const int row = idx >> 2, c4 = (idx & 3) * 8;
      *(uint4*)&s_wq[row][c4] = *(const uint4*)&qwT[row * 192 + ks * 32 + c4];
      *(uint4*)&s_wv[row][c4] = *(const uint4*)&vwT[row * 192 + ks * 32 + c4];
    }
    __syncthreads();
    const bf16x8 a = *(const bf16x8*)&s_xn0[wm * 16 + l15][ks * 32 + 8 * lg4];
#pragma unroll
    for (int f = 0; f < 6; ++f) {
      const bf16x8 bq = *(const bf16x8*)&s_wq[wn * 96 + 16 * f + l15][8 * lg4];
      const bf16x8 bv = *(const bf16x8*)&s_wv[wn * 96 + 16 * f + l15][8 * lg4];
      aq[f] = __builtin_amdgcn_mfma_f32_16x16x32_bf16(a, bq, aq[f], 0, 0, 0);
      av[f] = __builtin_amdgcn_mfma_f32_16x16x32_bf16(a, bv, av[f], 0, 0, 0);
    }
    __syncthreads();
  }

#pragma unroll
  for (int f = 0; f < 6; ++f) {
    const int col = wn * 96 + 16 * f + l15;
#pragma unroll
    for (int reg = 0; reg < 4; ++reg) {
      vT[((size_t)b * 192 + col) * 256 + n0 + rl + reg] = f2bf(av[f][reg]);
      s_q[rl + reg][col] = aq[f][reg];
    }
  }
  __syncthreads();

#pragma unroll
  for (int half = 0; half < 2; ++half) {
    const int tt = half * 16 + (t >> 4);
    const int lg = t & 15;
    float vals[12], mx = -1e30f;
#pragma unroll
    for (int m = 0; m < 12; ++m) {
      vals[m] = s_q[tt][lg + 16 * m];
      mx = fmaxf(mx, vals[m]);
    }
    mx = max16(mx);
    float s = 0.f;
#pragma unroll
    for (int m = 0; m < 12; ++m) {
      vals[m] = expf(vals[m] - mx);
      s += vals[m];
    }
    s = sum16(s);
    const float inv = 1.f / s;
#pragma unroll
    for (int m = 0; m < 12; ++m)
      qs_bf[((size_t)tok0 + tt) * 192 + lg + 16 * m] = f2bf(vals[m] * inv);
  }
}

// ---------------------------------------------------------------------------
// K3b (MFMA, M=16): KV^T[b][d][c] = sum_n vT[b][d][n]*keysT[b][c][n], K=256.
// ---------------------------------------------------------------------------
__global__ __launch_bounds__(256) void k3b_mfma(
    const ushort* __restrict__ vT, const ushort* __restrict__ keysT,
    ushort* __restrict__ kvT) {
  const int t = threadIdx.x;
  const int lane = t & 63, wid = t >> 6;
  const int l15 = lane & 15, lg4 = lane >> 4;
  const int b = blockIdx.x / 12;
  const int d0 = (blockIdx.x % 12) * 16;
  const int rl = 4 * lg4;

  __shared__ __align__(16) ushort s_a[16][264];
  __shared__ __align__(16) ushort s_w[192][40];

  const ushort* vbase = vT + ((size_t)b * 192 + d0) * 256;
#pragma unroll
  for (int i = 0; i < 2; ++i) {
    const int idx = t + 256 * i;
    const int row = idx >> 5, c8 = (idx & 31) * 8;
    *(uint4*)&s_a[row][c8] = *(const uint4*)&vbase[row * 256 + c8];
  }

  f32x4 acc[3];
#pragma unroll
  for (int f = 0; f < 3; ++f) acc[f] = (f32x4){0.f, 0.f, 0.f, 0.f};
  const ushort* kbase = keysT + (size_t)b * 192 * 256;
#pragma unroll 1
  for (int ks = 0; ks < 8; ++ks) {
#pragma unroll
    for (int i = 0; i < 3; ++i) {
      const int idx = t + 256 * i;
      const int row = idx >> 2, c4 = (idx & 3) * 8;
      *(uint4*)&s_w[row][c4] = *(const uint4*)&kbase[row * 256 + ks * 32 + c4];
    }
    __syncthreads();
    const bf16x8 a = *(const bf16x8*)&s_a[l15][ks * 32 + 8 * lg4];
#pragma unroll
    for (int f = 0; f < 3; ++f) {
      const bf16x8 bb = *(const bf16x8*)&s_w[wid * 48 + 16 * f + l15][8 * lg4];
      acc[f] = __builtin_amdgcn_mfma_f32_16x16x32_bf16(a, bb, acc[f], 0, 0, 0);
    }
    __syncthreads();
  }

#pragma unroll
  for (int f = 0; f < 3; ++f) {
    const int col = wid * 48 + 16 * f + l15;
#pragma unroll
    for (int reg = 0; reg < 4; ++reg)
      kvT[((size_t)b * 192 + d0 + rl + reg) * 192 + col] = f2bf(acc[f][reg]);
  }
}

// ---------------------------------------------------------------------------
// K3ca (MFMA, M=16, fused): o1 = qs@KV; residual; LN; FFN; residual -> xb;
// then (if fuse_next) LN(blk_ln[d+1]) -> q,v -> softmax -> qs_bf/vT for d+1.
// ---------------------------------------------------------------------------
__global__ __launch_bounds__(256) void k3ca_mfma(
    float* __restrict__ xb, ushort* __restrict__ qs_bf,
    const ushort* __restrict__ kvT, const float* __restrict__ lnw,
    const float* __restrict__ lnb, const ushort* __restrict__ f1T,
    const ushort* __restrict__ f2T, const float* __restrict__ f1b,
    const float* __restrict__ f2b, const float* __restrict__ g1,
    const float* __restrict__ g2, const ushort* __restrict__ qwT,
    const ushort* __restrict__ vwT, ushort* __restrict__ vT,
    int depth, int fuse_next) {
  const int t = threadIdx.x;
  const int lane = t & 63, wid = t >> 6;
  const int l15 = lane & 15, lg4 = lane >> 4;
  const int tok0 = blockIdx.x * 16;
  const int b = blockIdx.x >> 4;
  const int n0 = (blockIdx.x & 15) * 16;
  const int rl = 4 * lg4;

  __shared__ __align__(16) char smem[6400 + 15360 + 15360 + 6400 + 512];
  ushort (*s_a)[200] = (ushort(*)[200])smem;
  ushort (*s_w)[40] = (ushort(*)[40])(smem + 6400);
  ushort (*s_w2)[40] = (ushort(*)[40])(smem + 6400 + 15360);
  ushort (*s_ff)[200] = (ushort(*)[200])(smem + 6400 + 2 * 15360);
  float (*s_red)[8] = (float(*)[8])(smem + 6400 + 2 * 15360 + 6400);
  float (*s_q)[196] = (float(*)[196])(smem + 6400);

#pragma unroll
  for (int i = 0; i < 2; ++i) {
    const int idx = t + 256 * i;
    if (idx < 384) {
      const int row = idx / 24, c8 = (idx % 24) * 8;
      *(uint4*)&s_a[row][c8] =
          *(const uint4*)&qs_bf[((size_t)tok0 + row) * 192 + c8];
    }
  }
  __syncthreads();

  f32x4 o1[3];
#pragma unroll
  for (int f = 0; f < 3; ++f) o1[f] = (f32x4){0.f, 0.f, 0.f, 0.f};
  const ushort* kvb = kvT + (size_t)b * 36864;
#pragma unroll 1
  for (int ks = 0; ks < 6; ++ks) {
#pragma unroll
    for (int i = 0; i < 3; ++i) {
      const int idx = t + 256 * i;
      const int row = idx >> 2, c4 = (idx & 3) * 8;
      *(uint4*)&s_w[row][c4] = *(const uint4*)&kvb[row * 192 + ks * 32 + c4];
    }
    __syncthreads();
    const bf16x8 a = *(const bf16x8*)&s_a[l15][ks * 32 + 8 * lg4];
#pragma unroll
    for (int f = 0; f < 3; ++f) {
      const bf16x8 bb = *(const bf16x8*)&s_w[wid * 48 + 16 * f + l15][8 * lg4];
      o1[f] = __builtin_amdgcn_mfma_f32_16x16x32_bf16(a, bb, o1[f], 0, 0, 0);
    }
    __syncthreads();
  }

  const float* g1p = g1 + depth * 192;
  const float* lw = lnw + depth * 192;
  const float* lb = lnb + depth * 192;
  float xbn[3][4];
  {
    float psum[4] = {0.f, 0.f, 0.f, 0.f}, psq[4] = {0.f, 0.f, 0.f, 0.f};
#pragma unroll
    for (int f = 0; f < 3; ++f) {
      const int col = wid * 48 + 16 * f + l15;
#pragma unroll
      for (int reg = 0; reg < 4; ++reg) {
        const float xv =
            xb[((size_t)tok0 + rl + reg) * 192 + col] + o1[f][reg] * g1p[col];
        xbn[f][reg] = xv;
        psum[reg] += xv;
        psq[reg] = fmaf(xv, xv, psq[reg]);
      }
    }
#pragma unroll
    for (int reg = 0; reg < 4; ++reg) {
#pragma unroll
      for (int o = 8; o > 0; o >>= 1) {
        psum[reg] += __shfl_xor(psum[reg], o, 64);
        psq[reg] += __shfl_xor(psq[reg], o, 64);
      }
    }
    if (l15 == 0) {
#pragma unroll
      for (int reg = 0; reg < 4; ++reg) {
        s_red[rl + reg][wid] = psum[reg];
        s_red[rl + reg][4 + wid] = psq[reg];
      }
    }
  }
  __syncthreads();
  {
    float mean[4], inv[4];
#pragma unroll
    for (int reg = 0; reg < 4; ++reg) {
      const float s = s_red[rl + reg][0] + s_red[rl + reg][1] +
                      s_red[rl + reg][2] + s_red[rl + reg][3];
      const float q = s_red[rl + reg][4] + s_red[rl + reg][5] +
                      s_red[rl + reg][6] + s_red[rl + reg][7];
      mean[reg] = s * (1.f / 192.f);
      const float var = q * (1.f / 192.f) - mean[reg] * mean[reg];
      inv[reg] = rsqrtf(var + 1e-5f);
    }
#pragma unroll
    for (int f = 0; f < 3; ++f) {
      const int col = wid * 48 + 16 * f + l15;
#pragma unroll
      for (int reg = 0; reg < 4; ++reg)
        s_a[rl + reg][col] =
            f2bf((xbn[f][reg] - mean[reg]) * inv[reg] * lw[col] + lb[col]);
    }
  }
  __syncthreads();

  f32x4 o2[3];
#pragma unroll
  for (int f = 0; f < 3; ++f) o2[f] = (f32x4){0.f, 0.f, 0.f, 0.f};
#pragma unroll 1
  for (int h = 0; h < 2; ++h) {
    f32x4 hh[3];
#pragma unroll
    for (int f = 0; f < 3; ++f) hh[f] = (f32x4){0.f, 0.f, 0.f, 0.f};
    const ushort* f1base = f1T + depth * 73728 + h * 36864;
#pragma unroll 1
    for (int ks = 0; ks < 6; ++ks) {
#pragma unroll
      for (int i = 0; i < 3; ++i) {
        const int idx = t + 256 * i;
        const int row = idx >> 2, c4 = (idx & 3) * 8;
        *(uint4*)&s_w[row][c4] = *(const uint4*)&f1base[row * 192 + ks * 32 + c4];
      }
      __syncthreads();
      const bf16x8 a = *(const bf16x8*)&s_a[l15][ks * 32 + 8 * lg4];
#pragma unroll
      for (int f = 0; f < 3; ++f) {
        const bf16x8 bb = *(const bf16x8*)&s_w[wid * 48 + 16 * f + l15][8 * lg4];
        hh[f] = __builtin_amdgcn_mfma_f32_16x16x32_bf16(a, bb, hh[f], 0, 0, 0);
      }
      __syncthreads();
    }
    const float* b1p = f1b + depth * 384 + h * 192;
#pragma unroll
    for (int f = 0; f < 3; ++f) {
      const int col = wid * 48 + 16 * f + l15;
#pragma unroll
      for (int reg = 0; reg < 4; ++reg)
        s_ff[rl + reg][col] = f2bf(gelu_f(hh[f][reg] + b1p[col]));
    }
    __syncthreads();
    const ushort* f2base = f2T + depth * 73728;
#pragma unroll 1
    for (int ks2 = 0; ks2 < 6; ++ks2) {
#pragma unroll
      for (int i = 0; i < 3; ++i) {
        const int idx = t + 256 * i;
        const int row = idx >> 2, c4 = (idx & 3) * 8;
        *(uint4*)&s_w[row][c4] =
            *(const uint4*)&f2base[row * 384 + h * 192 + ks2 * 32 + c4];
      }
      __syncthreads();
      const bf16x8 a = *(const bf16x8*)&s_ff[l15][ks2 * 32 + 8 * lg4];
#pragma unroll
      for (int f = 0; f < 3; ++f) {
        const bf16x8 bb = *(const bf16x8*)&s_w[wid * 48 + 16 * f + l15][8 * lg4];
        o2[f] = __builtin_amdgcn_mfma_f32_16x16x32_bf16(a, bb, o2[f], 0, 0, 0);
      }
      __syncthreads();
    }
  }

  const float* b2p = f2b + depth * 192;
  const float* g2p = g2 + depth * 192;
  float xfin[3][4];
#pragma unroll
  for (int f = 0; f < 3; ++f) {
    const int col = wid * 48 + 16 * f + l15;
#pragma unroll
    for (int reg = 0; reg < 4; ++reg) {
      xfin[f][reg] = xbn[f][reg] + (o2[f][reg] + b2p[col]) * g2p[col];
      xb[((size_t)tok0 + rl + reg) * 192 + col] = xfin[f][reg];
    }
  }

  if (!fuse_next) return;

  {
    float psum[4] = {0.f, 0.f, 0.f, 0.f}, psq[4] = {0.f, 0.f, 0.f, 0.f};
#pragma unroll
    for (int f = 0; f < 3; ++f) {
#pragma unroll
      for (int reg = 0; reg < 4; ++reg) {
        psum[reg] += xfin[f][reg];
        psq[reg] = fmaf(xfin[f][reg], xfin[f][reg], psq[reg]);
      }
    }
#pragma unroll
    for (int reg = 0; reg < 4; ++reg) {
#pragma unroll
      for (int o = 8; o > 0; o >>= 1) {
        psum[reg] += __shfl_xor(psum[reg], o, 64);
        psq[reg] += __shfl_xor(psq[reg], o, 64);
      }
    }
    if (l15 == 0) {
#pragma unroll
      for (int reg = 0; reg < 4; ++reg) {
        s_red[rl + reg][wid] = psum[reg];
        s_red[rl + reg][4 + wid] = psq[reg];
      }
    }
  }
  __syncthreads();
  {
    const float* lw2 = lnw + (depth + 1) * 192;
    const float* lb2 = lnb + (depth + 1) * 192;
    float mean[4], inv[4];
#pragma unroll
    for (int reg = 0; reg < 4; ++reg) {
      const float s = s_red[rl + reg][0] + s_red[rl + reg][1] +
                      s_red[rl + reg][2] + s_red[rl + reg][3];
      const float q = s_red[rl + reg][4] + s_red[rl + reg][5] +
                      s_red[rl + reg][6] + s_red[rl + reg][7];
      mean[reg] = s * (1.f / 192.f);
      const float var = q * (1.f / 192.f) - mean[reg] * mean[reg];
      inv[reg] = rsqrtf(var + 1e-5f);
    }
#pragma unroll
    for (int f = 0; f < 3; ++f) {
      const int col = wid * 48 + 16 * f + l15;
#pragma unroll
      for (int reg = 0; reg < 4; ++reg)
        s_a[rl + reg][col] =
            f2bf((xfin[f][reg] - mean[reg]) * inv[reg] * lw2[col] + lb2[col]);
    }
  }
  __syncthreads();

  f32x4 aq[3], av[3];
#pragma unroll
  for (int f = 0; f < 3; ++f) {
    aq[f] = (f32x4){0.f, 0.f, 0.f, 0.f};
    av[f] = (f32x4){0.f, 0.f, 0.f, 0.f};
  }
  const ushort* qbase = qwT + (depth + 1) * 36864;
  const ushort* vbase = vwT + (depth + 1) * 36864;
#pragma unroll 1
  for (int ks = 0; ks < 6; ++ks) {
#pragma unroll
    for (int i = 0; i < 3; ++i) {
      const int idx = t + 256 * i;
      const int row = idx >> 2, c4 = (idx & 3) * 8;
      *(uint4*)&s_w[row][c4] = *(const uint4*)&qbase[row * 192 + ks * 32 + c4];
      *(uint4*)&s_w2[row][c4] = *(const uint4*)&vbase[row * 192 + ks * 32 + c4];
    }
    __syncthreads();
    const bf16x8 a = *(const bf16x8*)&s_a[l15][ks * 32 + 8 * lg4];
#pragma unroll
    for (int f = 0; f < 3; ++f) {
      const bf16x8 bq = *(const bf16x8*)&s_w[wid * 48 + 16 * f + l15][8 * lg4];
      const bf16x8 bv = *(const bf16x8*)&s_w2[wid * 48 + 16 * f + l15][8 * lg4];
      aq[f] = __builtin_amdgcn_mfma_f32_16x16x32_bf16(a, bq, aq[f], 0, 0, 0);
      av[f] = __builtin_amdgcn_mfma_f32_16x16x32_bf16(a, bv, av[f], 0, 0, 0);
    }
    __syncthreads();
  }

#pragma unroll
  for (int f = 0; f < 3; ++f) {
    const int col = wid * 48 + 16 * f + l15;
#pragma unroll
    for (int reg = 0; reg < 4; ++reg) {
      vT[((size_t)b * 192 + col) * 256 + n0 + rl + reg] = f2bf(av[f][reg]);
      s_q[rl + reg][col] = aq[f][reg];
    }
  }
  __syncthreads();

  {
    const int tt = t >> 4;
    const int lg = t & 15;
    float vals[12], mx = -1e30f;
#pragma unroll
    for (int m = 0; m < 12; ++m) {
      vals[m] = s_q[tt][lg + 16 * m];
      mx = fmaxf(mx, vals[m]);
    }
    mx = max16(mx);
    float s = 0.f;
#pragma unroll
    for (int m = 0; m < 12; ++m) {
      vals[m] = expf(vals[m] - mx);
      s += vals[m];
    }
    s = sum16(s);
    const float inv = 1.f / s;
#pragma unroll
    for (int m = 0; m < 12; ++m)
      qs_bf[((size_t)tok0 + tt) * 192 + lg + 16 * m] = f2bf(vals[m] * inv);
  }
}

// ---------------------------------------------------------------------------
// K4: feat = LN(mean_n xb); out = feat @ head_w + head_b.
// ---------------------------------------------------------------------------
__global__ __launch_bounds__(192) void k4_head(
    const float* __restrict__ xb, const float* __restrict__ flnw,
    const float* __restrict__ flnb, const float* __restrict__ hw,
    const float* __restrict__ hb, float* __restrict__ out) {
  const int b = blockIdx.x, t = threadIdx.x;
  const int w = t >> 6, lane = t & 63;
  float s = 0.f;
  const float* base = xb + (size_t)b * 256 * 192 + t;
#pragma unroll 4
  for (int n = 0; n < 256; ++n) s += base[n * 192];
  const float feat_pre = s * (1.f / 256.f);
  __shared__ float red[3];
  __shared__ float feat[192];
  float sm = wsum64(feat_pre);
  if (lane == 0) red[w] = sm;
  __syncthreads();
  const float mean = (red[0] + red[1] + red[2]) * (1.f / 192.f);
  __syncthreads();
  const float dd = feat_pre - mean;
  sm = wsum64(dd * dd);
  if (lane == 0) red[w] = sm;
  __syncthreads();
  const float var = (red[0] + red[1] + red[2]) * (1.f / 192.f);
  feat[t] = dd * rsqrtf(var + 1e-5f) * flnw[t] + flnb[t];
  __syncthreads();
  if (t < 9) {
    float a = hb[t];
    for (int d = 0; d < 192; ++d) a = fmaf(feat[d], hw[d * 9 + t], a);
    out[b * 9 + t] = a;
  }
}

// ---------------------------------------------------------------------------
extern "C" void kernel_launch(void* const* d_in, const int* in_sizes, int n_in,
                              void* d_out, int out_size, void* d_ws, size_t ws_size,
                              hipStream_t stream) {
  (void)in_sizes; (void)n_in; (void)out_size; (void)ws_size;
  const float* x          = (const float*)d_in[0];
  const float* band_w     = (const float*)d_in[1];
  const float* band_b     = (const float*)d_in[2];
  const float* dw_w       = (const float*)d_in[3];
  const float* pw_w       = (const float*)d_in[4];
  const float* pe_ln_w    = (const float*)d_in[5];
  const float* pe_ln_b    = (const float*)d_in[6];
  const float* spec_proto = (const float*)d_in[7];
  const float* spat_proto = (const float*)d_in[8];
  const float* r1_w       = (const float*)d_in[9];
  const float* r1_b       = (const float*)d_in[10];
  const float* r2_w       = (const float*)d_in[11];
  const float* r2_b       = (const float*)d_in[12];
  const float* key_w      = (const float*)d_in[13];
  const float* pos_bias   = (const float*)d_in[14];
  const float* blk_ln_w   = (const float*)d_in[15];
  const float* blk_ln_b   = (const float*)d_in[16];
  const float* blk_q_w    = (const float*)d_in[17];
  const float* blk_v_w    = (const float*)d_in[18];
  const float* blk_f1_w   = (const float*)d_in[19];
  const float* blk_f1_b   = (const float*)d_in[20];
  const float* blk_f2_w   = (const float*)d_in[21];
  const float* blk_f2_b   = (const float*)d_in[22];
  const float* blk_g1     = (const float*)d_in[23];
  const float* blk_g2     = (const float*)d_in[24];
  const float* fin_ln_w   = (const float*)d_in[25];
  const float* fin_ln_b   = (const float*)d_in[26];
  const float* head_w     = (const float*)d_in[27];
  const float* head_b     = (const float*)d_in[28];

  float* ws    = (float*)d_ws;
  float* dw    = ws;                   //    65,536 f32
  float* xbuf  = dw + 65536;           // 1,572,864 f32
  float* bandT = xbuf + 1572864;       //     1,024 f32 (824 used)
  ushort* ush    = (ushort*)(bandT + 1024);
  ushort* qs_bf  = ush;                // 1,572,864
  ushort* kvT    = qs_bf + 1572864;    // 1,179,648
  ushort* keysT  = kvT + 1179648;      // 1,572,864
  ushort* vT     = keysT + 1572864;    // 1,572,864
  ushort* qwT    = vT + 1572864;       //   110,592
  ushort* vwT    = qwT + 110592;       //   110,592
  ushort* f1T    = vwT + 110592;       //   221,184
  ushort* f2T    = f1T + 221184;       //   221,184
  ushort* r1T    = f2T + 221184;       //    24,576
  ushort* r2T    = r1T + 24576;        //     6,144
  ushort* keyT   = r2T + 6144;         //    43,008

  prep_w<<<864, 256, 0, stream>>>(blk_q_w, blk_v_w, blk_f1_w, blk_f2_w,
                                  r1_w, r2_w, key_w, band_w,
                                  qwT, vwT, f1T, f2T, r1T, r2T, keyT, bandT);
  k1_band_dw<<<512, 512, 0, stream>>>(x, bandT, band_b, dw_w, dw);
  k2_mfma<<<256, 256, 0, stream>>>(dw, pw_w, pe_ln_w, pe_ln_b, spec_proto,
                                   spat_proto, r1T, r1_b, r2T, r2_b, keyT,
                                   pos_bias, blk_ln_w, blk_ln_b, qwT, vwT,
                                   xbuf, keysT, qs_bf, vT);
  for (int d = 0; d < 3; ++d) {
    k3b_mfma<<<384, 256, 0, stream>>>(vT, keysT, kvT);
    k3ca_mfma<<<512, 256, 0, stream>>>(xbuf, qs_bf, kvT, blk_ln_w, blk_ln_b,
                                       f1T, f2T, blk_f1_b, blk_f2_b, blk_g1,
                                       blk_g2, qwT, vwT, vT, d, (d < 2) ? 1 : 0);
  }
  k4_head<<<32, 192, 0, stream>>>(xbuf, fin_ln_w, fin_ln_b, head_w, head_b,
                                  (float*)d_out);
}